// Round 7
// baseline (314.011 us; speedup 1.0000x reference)
//
#include <hip/hip_runtime.h>
#include <hip/hip_bf16.h>

#define N_NODES 100000
#define N_EDGES 3200000
#define CH 32
#define NK 9
#define KTOT 320                                // 288 z + 32 x (root plane)
#define RS 328                                  // LDS row stride (bf16) for zgemm

#define BNODES 256                              // destination nodes per bucket
#define NBUCK ((N_NODES + BNODES - 1) / BNODES) // 391
#define CURS_PAD 16
#define MAXB 9216                               // max edges/bucket (mean 8192, 11 sigma)
#define CHE 8192                                // edges per place chunk
#define NCHUNK ((N_EDGES + CHE - 1) / CHE)      // 391

typedef __hip_bfloat16 bf16;
typedef __attribute__((ext_vector_type(8))) short bf16x8;
typedef __attribute__((ext_vector_type(4))) float f32x4;

// ---------------------------------------------------------------------------
// Bucket histogram (global)
// ---------------------------------------------------------------------------
__global__ __launch_bounds__(256) void bhist_kernel(const int* __restrict__ ei_col,
                                                    int* __restrict__ hist) {
    __shared__ int h[NBUCK];
    for (int j = threadIdx.x; j < NBUCK; j += 256) h[j] = 0;
    __syncthreads();
    int stride = gridDim.x * 256;
    for (int e = blockIdx.x * 256 + threadIdx.x; e < N_EDGES; e += stride)
        atomicAdd(&h[ei_col[e] >> 8], 1);
    __syncthreads();
    for (int j = threadIdx.x; j < NBUCK; j += 256)
        if (h[j]) atomicAdd(&hist[j], h[j]);
}

// ---------------------------------------------------------------------------
// Single-block exclusive scan over buckets; writes bstart + sentinel + cursors
// ---------------------------------------------------------------------------
__global__ __launch_bounds__(1024) void bscan_kernel(const int* __restrict__ hist,
                                                     int* __restrict__ bstart,
                                                     int* __restrict__ cursor) {
    __shared__ int s[1024];
    int t = threadIdx.x;
    int a = (2 * t < NBUCK) ? hist[2 * t] : 0;
    int b = (2 * t + 1 < NBUCK) ? hist[2 * t + 1] : 0;
    s[t] = a + b;
    __syncthreads();
    for (int off = 1; off < 1024; off <<= 1) {
        int u = (t >= off) ? s[t - off] : 0;
        __syncthreads();
        s[t] += u;
        __syncthreads();
    }
    int excl = s[t] - (a + b);
    if (2 * t < NBUCK) {
        bstart[2 * t] = excl;
        cursor[2 * t * CURS_PAD] = excl;
    }
    if (2 * t + 1 < NBUCK) {
        bstart[2 * t + 1] = excl + a;
        cursor[(2 * t + 1) * CURS_PAD] = excl + a;
    }
    if (t == 1023) bstart[NBUCK] = s[1023];
}

// ---------------------------------------------------------------------------
// Place with per-block batch allocation (single-XCD line ownership).
// Record: {row(17b)|ia(1)|ib(1)|lc(8b), qa|qb}
// ---------------------------------------------------------------------------
__global__ __launch_bounds__(256) void place_kernel(const float* __restrict__ pseudo,
                                                    const int* __restrict__ ei,
                                                    int* __restrict__ cursor,
                                                    uint2* __restrict__ edata) {
    __shared__ int h[NBUCK];
    __shared__ int gb[NBUCK];
    int tid = threadIdx.x;
    int c0 = blockIdx.x * CHE;
    int cend = min(c0 + CHE, N_EDGES);

    for (int j = tid; j < NBUCK; j += 256) h[j] = 0;
    __syncthreads();
    for (int e = c0 + tid; e < cend; e += 256)
        atomicAdd(&h[ei[N_EDGES + e] >> 8], 1);
    __syncthreads();
    for (int j = tid; j < NBUCK; j += 256)
        gb[j] = h[j] ? atomicAdd(&cursor[j * CURS_PAD], h[j]) : 0;
    __syncthreads();

    for (int e = c0 + tid; e < cend; e += 256) {
        int col = ei[N_EDGES + e];
        int row = ei[e];
        float2 pp = ((const float2*)pseudo)[e];
        float pa = fminf(fmaxf(pp.x, 0.f), 1.f);
        float pb = fminf(fmaxf(pp.y, 0.f), 1.f);
        int ia = pa < 0.5f ? 0 : 1;
        int ib = pb < 0.5f ? 0 : 1;
        float wa1 = 2.f * (pa - 0.5f * (float)ia);
        float wb1 = 2.f * (pb - 0.5f * (float)ib);
        unsigned qa = (unsigned)(wa1 * 65535.f + 0.5f);
        unsigned qb = (unsigned)(wb1 * 65535.f + 0.5f);
        int pos = atomicAdd(&gb[col >> 8], 1);
        uint2 d;
        d.x = (unsigned)row | ((unsigned)ia << 17) | ((unsigned)ib << 18)
            | ((unsigned)(col & 255) << 20);
        d.y = qa | (qb << 16);
        edata[pos] = d;
    }
}

// ---------------------------------------------------------------------------
// Per-bucket counting sort by key=(lc,ia,ib) (1024 classes). Output records
// are {row_byte_offset, qa|qb}; per-node class counts packed 4x u16.
// ---------------------------------------------------------------------------
__global__ __launch_bounds__(256) void bsort_kernel(const int* __restrict__ bstart,
                                                    uint2* __restrict__ edata,
                                                    int* __restrict__ nstart,
                                                    uint2* __restrict__ ncnt4) {
    __shared__ uint2 buf[MAXB];   // 72 KB
    __shared__ int h[1024];       // 4 KB
    __shared__ int ex[1024];      // 4 KB
    __shared__ int tp[256];       // 1 KB
    int tid = threadIdx.x;
    int b = blockIdx.x;
    int e0 = bstart[b], e1 = bstart[b + 1];
    int sz = min(e1 - e0, MAXB);

    for (int j = tid; j < 1024; j += 256) h[j] = 0;
    for (int j = tid; j < sz; j += 256) buf[j] = edata[e0 + j];
    __syncthreads();
    for (int j = tid; j < sz; j += 256) {
        unsigned xx = buf[j].x;
        int key = (((xx >> 20) & 255) << 2) | (((xx >> 17) & 1) << 1) | ((xx >> 18) & 1);
        atomicAdd(&h[key], 1);
    }
    __syncthreads();
    int b0 = h[4 * tid], b1 = h[4 * tid + 1], b2 = h[4 * tid + 2], b3 = h[4 * tid + 3];
    int tsum = b0 + b1 + b2 + b3;
    tp[tid] = tsum;
    __syncthreads();
    for (int d = 1; d < 256; d <<= 1) {
        int u = (tid >= d) ? tp[tid - d] : 0;
        __syncthreads();
        tp[tid] += u;
        __syncthreads();
    }
    int ebase = tp[tid] - tsum;   // exclusive over thread groups
    ex[4 * tid]     = ebase;
    ex[4 * tid + 1] = ebase + b0;
    ex[4 * tid + 2] = ebase + b0 + b1;
    ex[4 * tid + 3] = ebase + b0 + b1 + b2;
    {
        int n = b * BNODES + tid;   // lc == tid
        if (n < N_NODES) {
            nstart[n] = e0 + ebase;
            ncnt4[n] = make_uint2((unsigned)b0 | ((unsigned)b1 << 16),
                                  (unsigned)b2 | ((unsigned)b3 << 16));
        }
    }
    __syncthreads();
    for (int j = tid; j < sz; j += 256) {
        uint2 r = buf[j];
        unsigned xx = r.x;
        int key = (((xx >> 20) & 255) << 2) | (((xx >> 17) & 1) << 1) | ((xx >> 18) & 1);
        int p = atomicAdd(&ex[key], 1);
        uint2 outr;
        outr.x = (xx & 0x1FFFF) << 7;   // row * 128 bytes
        outr.y = r.y;
        edata[e0 + p] = outr;
    }
}

// ---------------------------------------------------------------------------
// Per-node pull, class-sorted: 4 runs with fixed accumulator routing.
// One wave per node; halves alternate edges within each run.
// ---------------------------------------------------------------------------
__global__ __launch_bounds__(256) void gather_kernel(const float* __restrict__ x,
                                                     const int* __restrict__ nstart,
                                                     const uint2* __restrict__ ncnt4,
                                                     const uint2* __restrict__ edata,
                                                     bf16* __restrict__ za) {
    int tid = threadIdx.x;
    int wid = tid >> 6;
    int lane = tid & 63;
    int half = lane >> 5;
    int i = lane & 31;
    int ioff = i << 2;
    int n = blockIdx.x * 4 + wid;
    if (n >= N_NODES) return;

    const char* xb = (const char*)x;
    const uint2* ep = edata + nstart[n];
    uint2 cc = ncnt4[n];
    int c00 = cc.x & 0xFFFF, c01 = cc.x >> 16;
    int c10 = cc.y & 0xFFFF, c11 = cc.y >> 16;
    int dg = c00 + c01 + c10 + c11;

    float a0 = 0.f, a1 = 0.f, a2 = 0.f, a3 = 0.f, a4 = 0.f,
          a5 = 0.f, a6 = 0.f, a7 = 0.f, a8 = 0.f;

#define EDGE_LOOP(CNT, A0, A1, A2, A3)                                   \
    for (int j = half; j < (CNT); j += 2) {                              \
        uint2 ed = ep[j];                                                \
        float wa1v = (float)(ed.y & 0xFFFF) * (1.f / 65535.f);           \
        float wb1v = (float)(ed.y >> 16) * (1.f / 65535.f);              \
        float wb0v = 1.f - wb1v;                                         \
        float xv = *(const float*)(xb + (ed.x + ioff));                  \
        float t1 = wa1v * xv;                                            \
        float t0 = xv - t1;                                              \
        A0 += t0 * wb0v;  A1 += t0 * wb1v;                               \
        A2 += t1 * wb0v;  A3 += t1 * wb1v;                               \
    }                                                                    \
    ep += (CNT);

    EDGE_LOOP(c00, a0, a1, a3, a4)   // (ia,ib)=(0,0) -> planes 0,1,3,4
    EDGE_LOOP(c01, a1, a2, a4, a5)   // (0,1) -> planes 1,2,4,5
    EDGE_LOOP(c10, a3, a4, a6, a7)   // (1,0) -> planes 3,4,6,7
    EDGE_LOOP(c11, a4, a5, a7, a8)   // (1,1) -> planes 4,5,7,8
#undef EDGE_LOOP

    a0 += __shfl_down(a0, 32); a1 += __shfl_down(a1, 32); a2 += __shfl_down(a2, 32);
    a3 += __shfl_down(a3, 32); a4 += __shfl_down(a4, 32); a5 += __shfl_down(a5, 32);
    a6 += __shfl_down(a6, 32); a7 += __shfl_down(a7, 32); a8 += __shfl_down(a8, 32);

    if (half == 0) {
        float inv = 1.f / fmaxf((float)dg, 1.f);
        bf16* zr = za + (size_t)n * KTOT + i;
        zr[0 * CH] = __float2bfloat16(a0 * inv);
        zr[1 * CH] = __float2bfloat16(a1 * inv);
        zr[2 * CH] = __float2bfloat16(a2 * inv);
        zr[3 * CH] = __float2bfloat16(a3 * inv);
        zr[4 * CH] = __float2bfloat16(a4 * inv);
        zr[5 * CH] = __float2bfloat16(a5 * inv);
        zr[6 * CH] = __float2bfloat16(a6 * inv);
        zr[7 * CH] = __float2bfloat16(a7 * inv);
        zr[8 * CH] = __float2bfloat16(a8 * inv);
        zr[9 * CH] = __float2bfloat16(x[(size_t)n * CH + i]);
    }
}

// ---------------------------------------------------------------------------
// out = za @ [Wflat; root_w^T] + b  -- MFMA GEMM, M=100K, N=32, K=320
// ---------------------------------------------------------------------------
__global__ __launch_bounds__(256) void zgemm_kernel(const bf16* __restrict__ za,
                                                    const float* __restrict__ w,
                                                    const float* __restrict__ rw,
                                                    const float* __restrict__ rb,
                                                    float* __restrict__ out) {
    __shared__ bf16 alds[64 * RS];
    __shared__ bf16 blds[32 * RS];
    int tid = threadIdx.x;
    int n0 = blockIdx.x * 64;

    for (int idx = tid; idx < 288 * 32; idx += 256) {
        int kk = idx >> 5, o = idx & 31;
        blds[o * RS + kk] = __float2bfloat16(w[idx]);
    }
    for (int idx = tid; idx < 32 * 32; idx += 256) {
        int i = idx >> 5, o = idx & 31;
        blds[o * RS + 288 + i] = __float2bfloat16(rw[o * 32 + i]);
    }
    for (int it = 0; it < 10; ++it) {
        int j = it * 256 + tid;
        int r = j / 40;
        int c = (j - r * 40) * 8;
        int n = n0 + r;
        uint4 v = make_uint4(0, 0, 0, 0);
        if (n < N_NODES) v = *(const uint4*)(za + (size_t)n * KTOT + c);
        *(uint4*)(alds + r * RS + c) = v;
    }
    __syncthreads();

    int l = tid & 63, wt = tid >> 6;
    int lr = l & 15, lq = l >> 4;
    f32x4 acc0 = {0.f, 0.f, 0.f, 0.f};
    f32x4 acc1 = {0.f, 0.f, 0.f, 0.f};
#pragma unroll
    for (int ks = 0; ks < 10; ++ks) {
        int kk = ks * 32 + lq * 8;
        bf16x8 a  = *(const bf16x8*)(alds + (wt * 16 + lr) * RS + kk);
        bf16x8 b0 = *(const bf16x8*)(blds + lr * RS + kk);
        bf16x8 b1 = *(const bf16x8*)(blds + (lr + 16) * RS + kk);
        acc0 = __builtin_amdgcn_mfma_f32_16x16x32_bf16(a, b0, acc0, 0, 0, 0);
        acc1 = __builtin_amdgcn_mfma_f32_16x16x32_bf16(a, b1, acc1, 0, 0, 0);
    }

    float bias0 = rb[lr], bias1 = rb[lr + 16];
    int rbase = n0 + wt * 16 + lq * 4;
#pragma unroll
    for (int r = 0; r < 4; ++r) {
        int n = rbase + r;
        if (n < N_NODES) {
            out[(size_t)n * CH + lr]      = acc0[r] + bias0;
            out[(size_t)n * CH + lr + 16] = acc1[r] + bias1;
        }
    }
}

// ---------------------------------------------------------------------------
extern "C" void kernel_launch(void* const* d_in, const int* in_sizes, int n_in,
                              void* d_out, int out_size, void* d_ws, size_t ws_size,
                              hipStream_t stream) {
    const float* x      = (const float*)d_in[0];
    const float* pseudo = (const float*)d_in[1];
    const float* weight = (const float*)d_in[2];
    const float* root_w = (const float*)d_in[3];
    const float* root_b = (const float*)d_in[4];
    const int*   ei     = (const int*)d_in[5];
    float* out = (float*)d_out;

    int* hist    = (int*)d_ws;                  // 2048
    int* bstart  = hist + 2048;                 // 2048 (NBUCK+1 used)
    int* cursor  = bstart + 2048;               // NBUCK*16 = 6256 (pad 8192)
    int* nstart  = cursor + 8192;               // 100032
    uint2* ncnt4 = (uint2*)(nstart + 100032);   // 100032 uint2
    char* basep  = (char*)(ncnt4 + 100032);
    size_t off   = ((size_t)(basep - (char*)d_ws) + 1023) & ~(size_t)1023;
    uint2* edata = (uint2*)((char*)d_ws + off);      // 25.6 MB
    bf16* za     = (bf16*)(edata + N_EDGES);         // 64.0 MB

    hipMemsetAsync(hist, 0, NBUCK * sizeof(int), stream);
    bhist_kernel<<<256, 256, 0, stream>>>(ei + N_EDGES, hist);
    bscan_kernel<<<1, 1024, 0, stream>>>(hist, bstart, cursor);
    place_kernel<<<NCHUNK, 256, 0, stream>>>(pseudo, ei, cursor, edata);
    bsort_kernel<<<NBUCK, 256, 0, stream>>>(bstart, edata, nstart, ncnt4);
    gather_kernel<<<(N_NODES + 3) / 4, 256, 0, stream>>>(x, nstart, ncnt4, edata, za);
    zgemm_kernel<<<(N_NODES + 63) / 64, 256, 0, stream>>>(za, weight, root_w, root_b, out);
}

// Round 8
// 303.030 us; speedup vs baseline: 1.0362x; 1.0362x over previous
//
#include <hip/hip_runtime.h>
#include <hip/hip_bf16.h>

#define N_NODES 100000
#define N_EDGES 3200000
#define CH 32
#define NK 9
#define KTOT 320                                // 288 z + 32 x (root plane)
#define RS 328                                  // padded K stride (bf16)

#define BNODES 256                              // destination nodes per bucket
#define NBUCK ((N_NODES + BNODES - 1) / BNODES) // 391
#define CURS_PAD 16
#define MAXB 9216
#define CHE 8192
#define NCHUNK ((N_EDGES + CHE - 1) / CHE)      // 391

typedef __hip_bfloat16 bf16;
typedef __attribute__((ext_vector_type(8))) short bf16x8;
typedef __attribute__((ext_vector_type(4))) float f32x4;

// ---------------------------------------------------------------------------
// Prep: x -> bf16 copy; [weight | root_w^T] -> bf16 B-matrix in LDS layout
// Bg[o*RS + kk], kk = k*32+i for k<9, and Bg[o*RS + 288 + i] = rw[o][i]
// ---------------------------------------------------------------------------
__global__ __launch_bounds__(256) void prep_kernel(const float* __restrict__ x,
                                                   const float* __restrict__ w,
                                                   const float* __restrict__ rw,
                                                   bf16* __restrict__ xb,
                                                   bf16* __restrict__ Bg) {
    int idx = blockIdx.x * 256 + threadIdx.x;
    if (idx < N_NODES * CH / 4) {
        float4 v = ((const float4*)x)[idx];
        union { bf16 h[4]; uint2 u; } pk;
        pk.h[0] = __float2bfloat16(v.x);
        pk.h[1] = __float2bfloat16(v.y);
        pk.h[2] = __float2bfloat16(v.z);
        pk.h[3] = __float2bfloat16(v.w);
        ((uint2*)xb)[idx] = pk.u;
    }
    if (idx < NK * CH * CH) {           // w flat = [k][i][o] = kk*32 + o
        int kk = idx >> 5, o = idx & 31;
        Bg[o * RS + kk] = __float2bfloat16(w[idx]);
    }
    if (idx < CH * CH) {                // rw[o][i]
        int o = idx >> 5, i = idx & 31;
        Bg[o * RS + 288 + i] = __float2bfloat16(rw[idx]);
    }
}

// ---------------------------------------------------------------------------
// Bucket histogram (global)
// ---------------------------------------------------------------------------
__global__ __launch_bounds__(256) void bhist_kernel(const int* __restrict__ ei_col,
                                                    int* __restrict__ hist) {
    __shared__ int h[NBUCK];
    for (int j = threadIdx.x; j < NBUCK; j += 256) h[j] = 0;
    __syncthreads();
    int stride = gridDim.x * 256;
    for (int e = blockIdx.x * 256 + threadIdx.x; e < N_EDGES; e += stride)
        atomicAdd(&h[ei_col[e] >> 8], 1);
    __syncthreads();
    for (int j = threadIdx.x; j < NBUCK; j += 256)
        if (h[j]) atomicAdd(&hist[j], h[j]);
}

// ---------------------------------------------------------------------------
// Single-block exclusive scan over buckets; writes bstart + sentinel + cursors
// ---------------------------------------------------------------------------
__global__ __launch_bounds__(1024) void bscan_kernel(const int* __restrict__ hist,
                                                     int* __restrict__ bstart,
                                                     int* __restrict__ cursor) {
    __shared__ int s[1024];
    int t = threadIdx.x;
    int a = (2 * t < NBUCK) ? hist[2 * t] : 0;
    int b = (2 * t + 1 < NBUCK) ? hist[2 * t + 1] : 0;
    s[t] = a + b;
    __syncthreads();
    for (int off = 1; off < 1024; off <<= 1) {
        int u = (t >= off) ? s[t - off] : 0;
        __syncthreads();
        s[t] += u;
        __syncthreads();
    }
    int excl = s[t] - (a + b);
    if (2 * t < NBUCK) {
        bstart[2 * t] = excl;
        cursor[2 * t * CURS_PAD] = excl;
    }
    if (2 * t + 1 < NBUCK) {
        bstart[2 * t + 1] = excl + a;
        cursor[(2 * t + 1) * CURS_PAD] = excl + a;
    }
    if (t == 1023) bstart[NBUCK] = s[1023];
}

// ---------------------------------------------------------------------------
// Place with per-block batch allocation (single-XCD line ownership).
// ---------------------------------------------------------------------------
__global__ __launch_bounds__(256) void place_kernel(const float* __restrict__ pseudo,
                                                    const int* __restrict__ ei,
                                                    int* __restrict__ cursor,
                                                    uint2* __restrict__ edata) {
    __shared__ int h[NBUCK];
    __shared__ int gb[NBUCK];
    int tid = threadIdx.x;
    int c0 = blockIdx.x * CHE;
    int cend = min(c0 + CHE, N_EDGES);

    for (int j = tid; j < NBUCK; j += 256) h[j] = 0;
    __syncthreads();
    for (int e = c0 + tid; e < cend; e += 256)
        atomicAdd(&h[ei[N_EDGES + e] >> 8], 1);
    __syncthreads();
    for (int j = tid; j < NBUCK; j += 256)
        gb[j] = h[j] ? atomicAdd(&cursor[j * CURS_PAD], h[j]) : 0;
    __syncthreads();

    for (int e = c0 + tid; e < cend; e += 256) {
        int col = ei[N_EDGES + e];
        int row = ei[e];
        float2 pp = ((const float2*)pseudo)[e];
        float pa = fminf(fmaxf(pp.x, 0.f), 1.f);
        float pb = fminf(fmaxf(pp.y, 0.f), 1.f);
        int ia = pa < 0.5f ? 0 : 1;
        int ib = pb < 0.5f ? 0 : 1;
        float wa1 = 2.f * (pa - 0.5f * (float)ia);
        float wb1 = 2.f * (pb - 0.5f * (float)ib);
        unsigned qa = (unsigned)(wa1 * 65535.f + 0.5f);
        unsigned qb = (unsigned)(wb1 * 65535.f + 0.5f);
        int pos = atomicAdd(&gb[col >> 8], 1);
        uint2 d;
        d.x = (unsigned)row | ((unsigned)ia << 17) | ((unsigned)ib << 18)
            | ((unsigned)(col & 255) << 20);
        d.y = qa | (qb << 16);
        edata[pos] = d;
    }
}

// ---------------------------------------------------------------------------
// Per-bucket counting sort by key=(lc,ia,ib); records become
// {row*64 (bf16-row byte offset), qa|qb}; per-node class counts packed 4x u16.
// ---------------------------------------------------------------------------
__global__ __launch_bounds__(256) void bsort_kernel(const int* __restrict__ bstart,
                                                    uint2* __restrict__ edata,
                                                    int* __restrict__ nstart,
                                                    uint2* __restrict__ ncnt4) {
    __shared__ uint2 buf[MAXB];   // 72 KB
    __shared__ int h[1024];
    __shared__ int ex[1024];
    __shared__ int tp[256];
    int tid = threadIdx.x;
    int b = blockIdx.x;
    int e0 = bstart[b], e1 = bstart[b + 1];
    int sz = min(e1 - e0, MAXB);

    for (int j = tid; j < 1024; j += 256) h[j] = 0;
    for (int j = tid; j < sz; j += 256) buf[j] = edata[e0 + j];
    __syncthreads();
    for (int j = tid; j < sz; j += 256) {
        unsigned xx = buf[j].x;
        int key = (((xx >> 20) & 255) << 2) | (((xx >> 17) & 1) << 1) | ((xx >> 18) & 1);
        atomicAdd(&h[key], 1);
    }
    __syncthreads();
    int b0 = h[4 * tid], b1 = h[4 * tid + 1], b2 = h[4 * tid + 2], b3 = h[4 * tid + 3];
    int tsum = b0 + b1 + b2 + b3;
    tp[tid] = tsum;
    __syncthreads();
    for (int d = 1; d < 256; d <<= 1) {
        int u = (tid >= d) ? tp[tid - d] : 0;
        __syncthreads();
        tp[tid] += u;
        __syncthreads();
    }
    int ebase = tp[tid] - tsum;
    ex[4 * tid]     = ebase;
    ex[4 * tid + 1] = ebase + b0;
    ex[4 * tid + 2] = ebase + b0 + b1;
    ex[4 * tid + 3] = ebase + b0 + b1 + b2;
    {
        int n = b * BNODES + tid;
        if (n < N_NODES) {
            nstart[n] = e0 + ebase;
            ncnt4[n] = make_uint2((unsigned)b0 | ((unsigned)b1 << 16),
                                  (unsigned)b2 | ((unsigned)b3 << 16));
        }
    }
    __syncthreads();
    for (int j = tid; j < sz; j += 256) {
        uint2 r = buf[j];
        unsigned xx = r.x;
        int key = (((xx >> 20) & 255) << 2) | (((xx >> 17) & 1) << 1) | ((xx >> 18) & 1);
        int p = atomicAdd(&ex[key], 1);
        uint2 outr;
        outr.x = (xx & 0x1FFFF) << 6;   // row * 64 bytes (bf16 row)
        outr.y = r.y;
        edata[e0 + p] = outr;
    }
}

// ---------------------------------------------------------------------------
// Fused gather + MFMA: block = 16 nodes, 4 waves x 4 nodes. z -> LDS (bf16,
// padded RS), then one 16x320x32 MFMA phase writes out directly.
// ---------------------------------------------------------------------------
__global__ __launch_bounds__(256) void gather_mm_kernel(const bf16* __restrict__ xb,
                                                        const bf16* __restrict__ Bg,
                                                        const float* __restrict__ rb,
                                                        const int* __restrict__ nstart,
                                                        const uint2* __restrict__ ncnt4,
                                                        const uint2* __restrict__ edata,
                                                        float* __restrict__ out) {
    __shared__ __align__(16) bf16 blds[32 * RS];   // 20992 B
    __shared__ __align__(16) bf16 zlds[16 * RS];   // 10496 B
    int tid = threadIdx.x;

    for (int j = tid; j < 32 * RS / 8; j += 256)   // 1312 uint4 chunks
        ((uint4*)blds)[j] = ((const uint4*)Bg)[j];

    int wid = tid >> 6;
    int lane = tid & 63;
    int half = lane >> 5;
    int i = lane & 31;
    int ioff = i << 1;
    int n0 = blockIdx.x * 16;
    const char* xbb = (const char*)xb;

    for (int s = 0; s < 4; ++s) {
        int r = wid * 4 + s;
        int n = n0 + r;
        const uint2* ep = edata + nstart[n];
        uint2 cc = ncnt4[n];
        int c00 = cc.x & 0xFFFF, c01 = cc.x >> 16;
        int c10 = cc.y & 0xFFFF, c11 = cc.y >> 16;
        int dg = c00 + c01 + c10 + c11;

        float a0 = 0.f, a1 = 0.f, a2 = 0.f, a3 = 0.f, a4 = 0.f,
              a5 = 0.f, a6 = 0.f, a7 = 0.f, a8 = 0.f;

#define EDGE_FMA(ED, XV, A0, A1, A2, A3)                                 \
        {                                                                \
            float wa1v = (float)((ED).y & 0xFFFF) * (1.f / 65535.f);     \
            float wb1v = (float)((ED).y >> 16) * (1.f / 65535.f);        \
            float wb0v = 1.f - wb1v;                                     \
            float t1 = wa1v * (XV);                                      \
            float t0 = (XV) - t1;                                        \
            A0 += t0 * wb0v;  A1 += t0 * wb1v;                           \
            A2 += t1 * wb0v;  A3 += t1 * wb1v;                           \
        }

#define EDGE_RUN(CNT, A0, A1, A2, A3)                                    \
        {                                                                \
            int jb = half ? ((CNT) >> 1) : 0;                            \
            int je = half ? (CNT) : ((CNT) >> 1);                        \
            int j = jb;                                                  \
            for (; j + 1 < je; j += 2) {                                 \
                uint2 e0 = ep[j], e1 = ep[j + 1];                        \
                float x0 = __bfloat162float(*(const bf16*)(xbb + e0.x + ioff)); \
                float x1 = __bfloat162float(*(const bf16*)(xbb + e1.x + ioff)); \
                EDGE_FMA(e0, x0, A0, A1, A2, A3)                         \
                EDGE_FMA(e1, x1, A0, A1, A2, A3)                         \
            }                                                            \
            if (j < je) {                                                \
                uint2 e0 = ep[j];                                        \
                float x0 = __bfloat162float(*(const bf16*)(xbb + e0.x + ioff)); \
                EDGE_FMA(e0, x0, A0, A1, A2, A3)                         \
            }                                                            \
            ep += (CNT);                                                 \
        }

        EDGE_RUN(c00, a0, a1, a3, a4)   // (ia,ib)=(0,0) -> planes 0,1,3,4
        EDGE_RUN(c01, a1, a2, a4, a5)   // (0,1) -> planes 1,2,4,5
        EDGE_RUN(c10, a3, a4, a6, a7)   // (1,0) -> planes 3,4,6,7
        EDGE_RUN(c11, a4, a5, a7, a8)   // (1,1) -> planes 4,5,7,8
#undef EDGE_RUN
#undef EDGE_FMA

        a0 += __shfl_down(a0, 32); a1 += __shfl_down(a1, 32); a2 += __shfl_down(a2, 32);
        a3 += __shfl_down(a3, 32); a4 += __shfl_down(a4, 32); a5 += __shfl_down(a5, 32);
        a6 += __shfl_down(a6, 32); a7 += __shfl_down(a7, 32); a8 += __shfl_down(a8, 32);

        if (half == 0) {
            float inv = 1.f / fmaxf((float)dg, 1.f);
            bf16* zr = zlds + r * RS + i;
            zr[0 * CH] = __float2bfloat16(a0 * inv);
            zr[1 * CH] = __float2bfloat16(a1 * inv);
            zr[2 * CH] = __float2bfloat16(a2 * inv);
            zr[3 * CH] = __float2bfloat16(a3 * inv);
            zr[4 * CH] = __float2bfloat16(a4 * inv);
            zr[5 * CH] = __float2bfloat16(a5 * inv);
            zr[6 * CH] = __float2bfloat16(a6 * inv);
            zr[7 * CH] = __float2bfloat16(a7 * inv);
            zr[8 * CH] = __float2bfloat16(a8 * inv);
            zr[9 * CH] = xb[(size_t)n * CH + i];   // root plane
        }
    }
    __syncthreads();

    if (wid < 2) {   // wave 0 -> cols 0-15, wave 1 -> cols 16-31
        int lr = lane & 15, lq = lane >> 4;
        f32x4 acc = {0.f, 0.f, 0.f, 0.f};
#pragma unroll
        for (int ks = 0; ks < 10; ++ks) {
            int kk = ks * 32 + lq * 8;
            bf16x8 a = *(const bf16x8*)(zlds + lr * RS + kk);
            bf16x8 b = *(const bf16x8*)(blds + (lr + wid * 16) * RS + kk);
            acc = __builtin_amdgcn_mfma_f32_16x16x32_bf16(a, b, acc, 0, 0, 0);
        }
        float bias = rb[lr + wid * 16];
#pragma unroll
        for (int r = 0; r < 4; ++r) {
            int n = n0 + lq * 4 + r;
            out[(size_t)n * CH + lr + wid * 16] = acc[r] + bias;
        }
    }
}

// ---------------------------------------------------------------------------
extern "C" void kernel_launch(void* const* d_in, const int* in_sizes, int n_in,
                              void* d_out, int out_size, void* d_ws, size_t ws_size,
                              hipStream_t stream) {
    const float* x      = (const float*)d_in[0];
    const float* pseudo = (const float*)d_in[1];
    const float* weight = (const float*)d_in[2];
    const float* root_w = (const float*)d_in[3];
    const float* root_b = (const float*)d_in[4];
    const int*   ei     = (const int*)d_in[5];
    float* out = (float*)d_out;

    int* hist    = (int*)d_ws;                  // 2048
    int* bstart  = hist + 2048;                 // 2048 (NBUCK+1 used)
    int* cursor  = bstart + 2048;               // 8192 (NBUCK*16 used)
    int* nstart  = cursor + 8192;               // 100032
    uint2* ncnt4 = (uint2*)(nstart + 100032);   // 100032 uint2
    char* basep  = (char*)(ncnt4 + 100032);
    size_t off   = ((size_t)(basep - (char*)d_ws) + 1023) & ~(size_t)1023;
    uint2* edata = (uint2*)((char*)d_ws + off);      // 25.6 MB
    bf16* xb     = (bf16*)(edata + N_EDGES);         // 6.4 MB
    bf16* Bg     = xb + (size_t)N_NODES * CH;        // 21 KB

    hipMemsetAsync(hist, 0, NBUCK * sizeof(int), stream);
    prep_kernel<<<(N_NODES * CH / 4 + 255) / 256, 256, 0, stream>>>(x, weight, root_w, xb, Bg);
    bhist_kernel<<<256, 256, 0, stream>>>(ei + N_EDGES, hist);
    bscan_kernel<<<1, 1024, 0, stream>>>(hist, bstart, cursor);
    place_kernel<<<NCHUNK, 256, 0, stream>>>(pseudo, ei, cursor, edata);
    bsort_kernel<<<NBUCK, 256, 0, stream>>>(bstart, edata, nstart, ncnt4);
    gather_mm_kernel<<<N_NODES / 16, 256, 0, stream>>>(xb, Bg, root_b, nstart, ncnt4,
                                                       edata, out);
}

// Round 10
// 260.676 us; speedup vs baseline: 1.2046x; 1.1625x over previous
//
#include <hip/hip_runtime.h>
#include <hip/hip_bf16.h>

#define N_NODES 100000
#define N_EDGES 3200000
#define CH 32
#define NK 9
#define KTOT 320                                // 288 z + 32 x (root plane)
#define RS 328                                  // padded K stride (bf16)

#define BNODES 256                              // destination nodes per bucket
#define NBUCK ((N_NODES + BNODES - 1) / BNODES) // 391
#define CURS_PAD 16
#define MAXB 9216
#define CHE 8192
#define NCHUNK ((N_EDGES + CHE - 1) / CHE)      // 391

typedef __hip_bfloat16 bf16;
typedef __attribute__((ext_vector_type(8))) short bf16x8;
typedef __attribute__((ext_vector_type(4))) float f32x4;

// ---------------------------------------------------------------------------
// Prep: x -> bf16 copy; [weight | root_w^T] -> bf16 B-matrix (MFMA row layout)
// ---------------------------------------------------------------------------
__global__ __launch_bounds__(256) void prep_kernel(const float* __restrict__ x,
                                                   const float* __restrict__ w,
                                                   const float* __restrict__ rw,
                                                   bf16* __restrict__ xb,
                                                   bf16* __restrict__ Bg) {
    int idx = blockIdx.x * 256 + threadIdx.x;
    if (idx < N_NODES * CH / 4) {
        float4 v = ((const float4*)x)[idx];
        union { bf16 h[4]; uint2 u; } pk;
        pk.h[0] = __float2bfloat16(v.x);
        pk.h[1] = __float2bfloat16(v.y);
        pk.h[2] = __float2bfloat16(v.z);
        pk.h[3] = __float2bfloat16(v.w);
        ((uint2*)xb)[idx] = pk.u;
    }
    if (idx < NK * CH * CH) {           // w flat = [k][i][o] = kk*32 + o
        int kk = idx >> 5, o = idx & 31;
        Bg[o * RS + kk] = __float2bfloat16(w[idx]);
    }
    if (idx < CH * CH) {                // rw[o][i]
        int o = idx >> 5, i = idx & 31;
        Bg[o * RS + 288 + i] = __float2bfloat16(rw[idx]);
    }
}

// ---------------------------------------------------------------------------
// Bucket histogram (global)
// ---------------------------------------------------------------------------
__global__ __launch_bounds__(256) void bhist_kernel(const int* __restrict__ ei_col,
                                                    int* __restrict__ hist) {
    __shared__ int h[NBUCK];
    for (int j = threadIdx.x; j < NBUCK; j += 256) h[j] = 0;
    __syncthreads();
    int stride = gridDim.x * 256;
    for (int e = blockIdx.x * 256 + threadIdx.x; e < N_EDGES; e += stride)
        atomicAdd(&h[ei_col[e] >> 8], 1);
    __syncthreads();
    for (int j = threadIdx.x; j < NBUCK; j += 256)
        if (h[j]) atomicAdd(&hist[j], h[j]);
}

// ---------------------------------------------------------------------------
// Single-block exclusive scan over buckets; writes bstart + sentinel + cursors
// ---------------------------------------------------------------------------
__global__ __launch_bounds__(1024) void bscan_kernel(const int* __restrict__ hist,
                                                     int* __restrict__ bstart,
                                                     int* __restrict__ cursor) {
    __shared__ int s[1024];
    int t = threadIdx.x;
    int a = (2 * t < NBUCK) ? hist[2 * t] : 0;
    int b = (2 * t + 1 < NBUCK) ? hist[2 * t + 1] : 0;
    s[t] = a + b;
    __syncthreads();
    for (int off = 1; off < 1024; off <<= 1) {
        int u = (t >= off) ? s[t - off] : 0;
        __syncthreads();
        s[t] += u;
        __syncthreads();
    }
    int excl = s[t] - (a + b);
    if (2 * t < NBUCK) {
        bstart[2 * t] = excl;
        cursor[2 * t * CURS_PAD] = excl;
    }
    if (2 * t + 1 < NBUCK) {
        bstart[2 * t + 1] = excl + a;
        cursor[(2 * t + 1) * CURS_PAD] = excl + a;
    }
    if (t == 1023) bstart[NBUCK] = s[1023];
}

// ---------------------------------------------------------------------------
// Place with per-block batch allocation (single-XCD line ownership).
// ---------------------------------------------------------------------------
__global__ __launch_bounds__(256) void place_kernel(const float* __restrict__ pseudo,
                                                    const int* __restrict__ ei,
                                                    int* __restrict__ cursor,
                                                    uint2* __restrict__ edata) {
    __shared__ int h[NBUCK];
    __shared__ int gb[NBUCK];
    int tid = threadIdx.x;
    int c0 = blockIdx.x * CHE;
    int cend = min(c0 + CHE, N_EDGES);

    for (int j = tid; j < NBUCK; j += 256) h[j] = 0;
    __syncthreads();
    for (int e = c0 + tid; e < cend; e += 256)
        atomicAdd(&h[ei[N_EDGES + e] >> 8], 1);
    __syncthreads();
    for (int j = tid; j < NBUCK; j += 256)
        gb[j] = h[j] ? atomicAdd(&cursor[j * CURS_PAD], h[j]) : 0;
    __syncthreads();

    for (int e = c0 + tid; e < cend; e += 256) {
        int col = ei[N_EDGES + e];
        int row = ei[e];
        float2 pp = ((const float2*)pseudo)[e];
        float pa = fminf(fmaxf(pp.x, 0.f), 1.f);
        float pb = fminf(fmaxf(pp.y, 0.f), 1.f);
        int ia = pa < 0.5f ? 0 : 1;
        int ib = pb < 0.5f ? 0 : 1;
        float wa1 = 2.f * (pa - 0.5f * (float)ia);
        float wb1 = 2.f * (pb - 0.5f * (float)ib);
        unsigned qa = (unsigned)(wa1 * 65535.f + 0.5f);
        unsigned qb = (unsigned)(wb1 * 65535.f + 0.5f);
        int pos = atomicAdd(&gb[col >> 8], 1);
        uint2 d;
        d.x = (unsigned)row | ((unsigned)ia << 17) | ((unsigned)ib << 18)
            | ((unsigned)(col & 255) << 20);
        d.y = qa | (qb << 16);
        edata[pos] = d;
    }
}

// ---------------------------------------------------------------------------
// Per-bucket counting sort by key=(lc,ia,ib); output records:
// {row*64 (bf16-row byte off), wa1_bf16 | wb1_bf16<<16}; counts packed 4x u16.
// ---------------------------------------------------------------------------
__global__ __launch_bounds__(256) void bsort_kernel(const int* __restrict__ bstart,
                                                    uint2* __restrict__ edata,
                                                    int* __restrict__ nstart,
                                                    uint2* __restrict__ ncnt4) {
    __shared__ uint2 buf[MAXB];   // 72 KB
    __shared__ int h[1024];
    __shared__ int ex[1024];
    __shared__ int tp[256];
    int tid = threadIdx.x;
    int b = blockIdx.x;
    int e0 = bstart[b], e1 = bstart[b + 1];
    int sz = min(e1 - e0, MAXB);

    for (int j = tid; j < 1024; j += 256) h[j] = 0;
    for (int j = tid; j < sz; j += 256) buf[j] = edata[e0 + j];
    __syncthreads();
    for (int j = tid; j < sz; j += 256) {
        unsigned xx = buf[j].x;
        int key = (((xx >> 20) & 255) << 2) | (((xx >> 17) & 1) << 1) | ((xx >> 18) & 1);
        atomicAdd(&h[key], 1);
    }
    __syncthreads();
    int b0 = h[4 * tid], b1 = h[4 * tid + 1], b2 = h[4 * tid + 2], b3 = h[4 * tid + 3];
    int tsum = b0 + b1 + b2 + b3;
    tp[tid] = tsum;
    __syncthreads();
    for (int d = 1; d < 256; d <<= 1) {
        int u = (tid >= d) ? tp[tid - d] : 0;
        __syncthreads();
        tp[tid] += u;
        __syncthreads();
    }
    int ebase = tp[tid] - tsum;
    ex[4 * tid]     = ebase;
    ex[4 * tid + 1] = ebase + b0;
    ex[4 * tid + 2] = ebase + b0 + b1;
    ex[4 * tid + 3] = ebase + b0 + b1 + b2;
    {
        int n = b * BNODES + tid;
        if (n < N_NODES) {
            nstart[n] = e0 + ebase;
            ncnt4[n] = make_uint2((unsigned)b0 | ((unsigned)b1 << 16),
                                  (unsigned)b2 | ((unsigned)b3 << 16));
        }
    }
    __syncthreads();
    for (int j = tid; j < sz; j += 256) {
        uint2 r = buf[j];
        unsigned xx = r.x;
        int key = (((xx >> 20) & 255) << 2) | (((xx >> 17) & 1) << 1) | ((xx >> 18) & 1);
        int p = atomicAdd(&ex[key], 1);
        // convert u16 weights -> bf16 bit-packed (decode = shift-reinterpret)
        float wa1f = (float)(r.y & 0xFFFF) * (1.f / 65535.f);
        float wb1f = (float)(r.y >> 16) * (1.f / 65535.f);
        unsigned wa1b = __float_as_uint(wa1f) >> 16;
        unsigned wb1b = __float_as_uint(wb1f) >> 16;
        uint2 outr;
        outr.x = (xx & 0x1FFFF) << 6;   // row * 64 bytes (bf16 row)
        outr.y = wa1b | (wb1b << 16);
        edata[e0 + p] = outr;
    }
}

// ---------------------------------------------------------------------------
// Fused gather + MFMA: block = 16 nodes, 4 waves x 4 nodes. z -> LDS only
// (10.5 KB); MFMA B-frags read from global Bg (L2-hot). Chunk-4 prefetch.
// ---------------------------------------------------------------------------
__global__ __launch_bounds__(256, 6) void gather_mm_kernel(const bf16* __restrict__ xb,
                                                           const bf16* __restrict__ Bg,
                                                           const float* __restrict__ rb,
                                                           const int* __restrict__ nstart,
                                                           const uint2* __restrict__ ncnt4,
                                                           const uint2* __restrict__ edata,
                                                           float* __restrict__ out) {
    __shared__ __align__(16) bf16 zlds[16 * RS];   // 10496 B
    int tid = threadIdx.x;
    int wid = tid >> 6;
    int lane = tid & 63;
    int half = lane >> 5;
    int i = lane & 31;
    int ioff = i << 1;
    int n0 = blockIdx.x * 16;
    const char* xbb = (const char*)xb;

    for (int s = 0; s < 4; ++s) {
        int r = wid * 4 + s;
        int n = n0 + r;
        const uint2* ep = edata + nstart[n];
        uint2 cc = ncnt4[n];
        int c00 = cc.x & 0xFFFF, c01 = cc.x >> 16;
        int c10 = cc.y & 0xFFFF, c11 = cc.y >> 16;
        int dg = c00 + c01 + c10 + c11;

        float a0 = 0.f, a1 = 0.f, a2 = 0.f, a3 = 0.f, a4 = 0.f,
              a5 = 0.f, a6 = 0.f, a7 = 0.f, a8 = 0.f;

#define EDGE_FMA(ED, XV, A0, A1, A2, A3)                                 \
        {                                                                \
            float wa1v = __uint_as_float((ED).y << 16);                  \
            float wb1v = __uint_as_float((ED).y & 0xFFFF0000u);          \
            float wb0v = 1.f - wb1v;                                     \
            float t1 = wa1v * (XV);                                      \
            float t0 = (XV) - t1;                                        \
            A0 += t0 * wb0v;  A1 += t0 * wb1v;                           \
            A2 += t1 * wb0v;  A3 += t1 * wb1v;                           \
        }

#define XLOAD(ED) __bfloat162float(*(const bf16*)(xbb + (ED).x + ioff))

#define EDGE_RUN(CNT, A0, A1, A2, A3)                                    \
        {                                                                \
            int jb = half ? ((CNT) >> 1) : 0;                            \
            int je = half ? (CNT) : ((CNT) >> 1);                        \
            int j = jb;                                                  \
            for (; j + 3 < je; j += 4) {                                 \
                uint2 e0 = ep[j], e1 = ep[j + 1], e2 = ep[j + 2], e3 = ep[j + 3]; \
                float x0 = XLOAD(e0);                                    \
                float x1 = XLOAD(e1);                                    \
                float x2 = XLOAD(e2);                                    \
                float x3 = XLOAD(e3);                                    \
                EDGE_FMA(e0, x0, A0, A1, A2, A3)                         \
                EDGE_FMA(e1, x1, A0, A1, A2, A3)                         \
                EDGE_FMA(e2, x2, A0, A1, A2, A3)                         \
                EDGE_FMA(e3, x3, A0, A1, A2, A3)                         \
            }                                                            \
            for (; j < je; ++j) {                                        \
                uint2 e0 = ep[j];                                        \
                float x0 = XLOAD(e0);                                    \
                EDGE_FMA(e0, x0, A0, A1, A2, A3)                         \
            }                                                            \
            ep += (CNT);                                                 \
        }

        EDGE_RUN(c00, a0, a1, a3, a4)   // (ia,ib)=(0,0) -> planes 0,1,3,4
        EDGE_RUN(c01, a1, a2, a4, a5)   // (0,1) -> planes 1,2,4,5
        EDGE_RUN(c10, a3, a4, a6, a7)   // (1,0) -> planes 3,4,6,7
        EDGE_RUN(c11, a4, a5, a7, a8)   // (1,1) -> planes 4,5,7,8
#undef EDGE_RUN
#undef XLOAD
#undef EDGE_FMA

        a0 += __shfl_down(a0, 32); a1 += __shfl_down(a1, 32); a2 += __shfl_down(a2, 32);
        a3 += __shfl_down(a3, 32); a4 += __shfl_down(a4, 32); a5 += __shfl_down(a5, 32);
        a6 += __shfl_down(a6, 32); a7 += __shfl_down(a7, 32); a8 += __shfl_down(a8, 32);

        if (half == 0) {
            float inv = 1.f / fmaxf((float)dg, 1.f);
            bf16* zr = zlds + r * RS + i;
            zr[0 * CH] = __float2bfloat16(a0 * inv);
            zr[1 * CH] = __float2bfloat16(a1 * inv);
            zr[2 * CH] = __float2bfloat16(a2 * inv);
            zr[3 * CH] = __float2bfloat16(a3 * inv);
            zr[4 * CH] = __float2bfloat16(a4 * inv);
            zr[5 * CH] = __float2bfloat16(a5 * inv);
            zr[6 * CH] = __float2bfloat16(a6 * inv);
            zr[7 * CH] = __float2bfloat16(a7 * inv);
            zr[8 * CH] = __float2bfloat16(a8 * inv);
            zr[9 * CH] = xb[(size_t)n * CH + i];   // root plane
        }
    }
    __syncthreads();

    if (wid < 2) {   // wave 0 -> cols 0-15, wave 1 -> cols 16-31
        int lr = lane & 15, lq = lane >> 4;
        const bf16* brow = Bg + (size_t)(lr + wid * 16) * RS;
        f32x4 acc = {0.f, 0.f, 0.f, 0.f};
#pragma unroll
        for (int ks = 0; ks < 10; ++ks) {
            int kk = ks * 32 + lq * 8;
            bf16x8 a = *(const bf16x8*)(zlds + lr * RS + kk);
            bf16x8 b = *(const bf16x8*)(brow + kk);        // global, L2-hot
            acc = __builtin_amdgcn_mfma_f32_16x16x32_bf16(a, b, acc, 0, 0, 0);
        }
        float bias = rb[lr + wid * 16];
#pragma unroll
        for (int r = 0; r < 4; ++r) {
            int n = n0 + lq * 4 + r;
            out[(size_t)n * CH + lr + wid * 16] = acc[r] + bias;
        }
    }
}

// ---------------------------------------------------------------------------
extern "C" void kernel_launch(void* const* d_in, const int* in_sizes, int n_in,
                              void* d_out, int out_size, void* d_ws, size_t ws_size,
                              hipStream_t stream) {
    const float* x      = (const float*)d_in[0];
    const float* pseudo = (const float*)d_in[1];
    const float* weight = (const float*)d_in[2];
    const float* root_w = (const float*)d_in[3];
    const float* root_b = (const float*)d_in[4];
    const int*   ei     = (const int*)d_in[5];
    float* out = (float*)d_out;

    int* hist    = (int*)d_ws;                  // 2048
    int* bstart  = hist + 2048;                 // 2048 (NBUCK+1 used)
    int* cursor  = bstart + 2048;               // 8192 (NBUCK*16 used)
    int* nstart  = cursor + 8192;               // 100032
    uint2* ncnt4 = (uint2*)(nstart + 100032);   // 100032 uint2
    char* basep  = (char*)(ncnt4 + 100032);
    size_t off   = ((size_t)(basep - (char*)d_ws) + 1023) & ~(size_t)1023;
    uint2* edata = (uint2*)((char*)d_ws + off);      // 25.6 MB
    bf16* xb     = (bf16*)(edata + N_EDGES);         // 6.4 MB
    bf16* Bg     = xb + (size_t)N_NODES * CH;        // 21 KB

    hipMemsetAsync(hist, 0, NBUCK * sizeof(int), stream);
    prep_kernel<<<(N_NODES * CH / 4 + 255) / 256, 256, 0, stream>>>(x, weight, root_w, xb, Bg);
    bhist_kernel<<<256, 256, 0, stream>>>(ei + N_EDGES, hist);
    bscan_kernel<<<1, 1024, 0, stream>>>(hist, bstart, cursor);
    place_kernel<<<NCHUNK, 256, 0, stream>>>(pseudo, ei, cursor, edata);
    bsort_kernel<<<NBUCK, 256, 0, stream>>>(bstart, edata, nstart, ncnt4);
    gather_mm_kernel<<<N_NODES / 16, 256, 0, stream>>>(xb, Bg, root_b, nstart, ncnt4,
                                                       edata, out);
}

// Round 11
// 248.193 us; speedup vs baseline: 1.2652x; 1.0503x over previous
//
#include <hip/hip_runtime.h>
#include <hip/hip_bf16.h>

#define N_NODES 100000
#define N_EDGES 3200000
#define CH 32
#define NK 9
#define KTOT 320                                // 288 z + 32 x (root plane)
#define RS 328                                  // padded K stride (bf16)

#define BNODES 128                              // destination nodes per bucket
#define NBUCK ((N_NODES + BNODES - 1) / BNODES) // 782
#define CURS_PAD 16
#define MAXB 4800                               // mean 4093, ~11 sigma margin
#define CHE 8192
#define NCHUNK ((N_EDGES + CHE - 1) / CHE)      // 391

typedef __hip_bfloat16 bf16;
typedef __attribute__((ext_vector_type(8))) short bf16x8;
typedef __attribute__((ext_vector_type(4))) float f32x4;

// ---------------------------------------------------------------------------
// Prep: x -> bf16 copy; [weight | root_w^T] -> bf16 B-matrix (MFMA row layout)
// ---------------------------------------------------------------------------
__global__ __launch_bounds__(256) void prep_kernel(const float* __restrict__ x,
                                                   const float* __restrict__ w,
                                                   const float* __restrict__ rw,
                                                   bf16* __restrict__ xb,
                                                   bf16* __restrict__ Bg) {
    int idx = blockIdx.x * 256 + threadIdx.x;
    if (idx < N_NODES * CH / 4) {
        float4 v = ((const float4*)x)[idx];
        union { bf16 h[4]; uint2 u; } pk;
        pk.h[0] = __float2bfloat16(v.x);
        pk.h[1] = __float2bfloat16(v.y);
        pk.h[2] = __float2bfloat16(v.z);
        pk.h[3] = __float2bfloat16(v.w);
        ((uint2*)xb)[idx] = pk.u;
    }
    if (idx < NK * CH * CH) {           // w flat = [k][i][o] = kk*32 + o
        int kk = idx >> 5, o = idx & 31;
        Bg[o * RS + kk] = __float2bfloat16(w[idx]);
    }
    if (idx < CH * CH) {                // rw[o][i]
        int o = idx >> 5, i = idx & 31;
        Bg[o * RS + 288 + i] = __float2bfloat16(rw[idx]);
    }
}

// ---------------------------------------------------------------------------
// Bucket histogram (global), int4-vectorized
// ---------------------------------------------------------------------------
__global__ __launch_bounds__(256) void bhist_kernel(const int* __restrict__ ei_col,
                                                    int* __restrict__ hist) {
    __shared__ int h[NBUCK];
    for (int j = threadIdx.x; j < NBUCK; j += 256) h[j] = 0;
    __syncthreads();
    const int4* c4 = (const int4*)ei_col;
    int stride = gridDim.x * 256;
    for (int e = blockIdx.x * 256 + threadIdx.x; e < N_EDGES / 4; e += stride) {
        int4 v = c4[e];
        atomicAdd(&h[v.x >> 7], 1);
        atomicAdd(&h[v.y >> 7], 1);
        atomicAdd(&h[v.z >> 7], 1);
        atomicAdd(&h[v.w >> 7], 1);
    }
    __syncthreads();
    for (int j = threadIdx.x; j < NBUCK; j += 256)
        if (h[j]) atomicAdd(&hist[j], h[j]);
}

// ---------------------------------------------------------------------------
// Single-block exclusive scan over buckets; writes bstart + sentinel + cursors
// ---------------------------------------------------------------------------
__global__ __launch_bounds__(1024) void bscan_kernel(const int* __restrict__ hist,
                                                     int* __restrict__ bstart,
                                                     int* __restrict__ cursor) {
    __shared__ int s[1024];
    int t = threadIdx.x;
    int a = (2 * t < NBUCK) ? hist[2 * t] : 0;
    int b = (2 * t + 1 < NBUCK) ? hist[2 * t + 1] : 0;
    s[t] = a + b;
    __syncthreads();
    for (int off = 1; off < 1024; off <<= 1) {
        int u = (t >= off) ? s[t - off] : 0;
        __syncthreads();
        s[t] += u;
        __syncthreads();
    }
    int excl = s[t] - (a + b);
    if (2 * t < NBUCK) {
        bstart[2 * t] = excl;
        cursor[2 * t * CURS_PAD] = excl;
    }
    if (2 * t + 1 < NBUCK) {
        bstart[2 * t + 1] = excl + a;
        cursor[(2 * t + 1) * CURS_PAD] = excl + a;
    }
    if (t == 1023) bstart[NBUCK] = s[1023];
}

// ---------------------------------------------------------------------------
// Place with per-block batch allocation (single-XCD line ownership).
// Record: {row(17b)|ia(1)|ib(1)|lc(7b), qa|qb}
// ---------------------------------------------------------------------------
__global__ __launch_bounds__(256) void place_kernel(const float* __restrict__ pseudo,
                                                    const int* __restrict__ ei,
                                                    int* __restrict__ cursor,
                                                    uint2* __restrict__ edata) {
    __shared__ int h[NBUCK];
    __shared__ int gb[NBUCK];
    int tid = threadIdx.x;
    int c0 = blockIdx.x * CHE;
    int cend = min(c0 + CHE, N_EDGES);

    for (int j = tid; j < NBUCK; j += 256) h[j] = 0;
    __syncthreads();
    for (int e = c0 + tid; e < cend; e += 256)
        atomicAdd(&h[ei[N_EDGES + e] >> 7], 1);
    __syncthreads();
    for (int j = tid; j < NBUCK; j += 256)
        gb[j] = h[j] ? atomicAdd(&cursor[j * CURS_PAD], h[j]) : 0;
    __syncthreads();

    for (int e = c0 + tid; e < cend; e += 256) {
        int col = ei[N_EDGES + e];
        int row = ei[e];
        float2 pp = ((const float2*)pseudo)[e];
        float pa = fminf(fmaxf(pp.x, 0.f), 1.f);
        float pb = fminf(fmaxf(pp.y, 0.f), 1.f);
        int ia = pa < 0.5f ? 0 : 1;
        int ib = pb < 0.5f ? 0 : 1;
        float wa1 = 2.f * (pa - 0.5f * (float)ia);
        float wb1 = 2.f * (pb - 0.5f * (float)ib);
        unsigned qa = (unsigned)(wa1 * 65535.f + 0.5f);
        unsigned qb = (unsigned)(wb1 * 65535.f + 0.5f);
        int pos = atomicAdd(&gb[col >> 7], 1);
        uint2 d;
        d.x = (unsigned)row | ((unsigned)ia << 17) | ((unsigned)ib << 18)
            | ((unsigned)(col & 127) << 20);
        d.y = qa | (qb << 16);
        edata[pos] = d;
    }
}

// ---------------------------------------------------------------------------
// Per-bucket counting sort by key=(lc,ia,ib) (512 classes). Output records:
// {row*64 (bf16-row byte off), wa1_bf16 | wb1_bf16<<16}; counts packed 4x u16.
// LDS ~43 KB -> 3 blocks/CU (vs 1 before).
// ---------------------------------------------------------------------------
__global__ __launch_bounds__(256) void bsort_kernel(const int* __restrict__ bstart,
                                                    uint2* __restrict__ edata,
                                                    int* __restrict__ nstart,
                                                    uint2* __restrict__ ncnt4) {
    __shared__ uint2 buf[MAXB];   // 38.4 KB
    __shared__ int h[4 * BNODES];   // 512 keys
    __shared__ int ex[4 * BNODES];
    __shared__ int tp[256];
    int tid = threadIdx.x;
    int b = blockIdx.x;
    int e0 = bstart[b], e1 = bstart[b + 1];
    int sz = min(e1 - e0, MAXB);

    for (int j = tid; j < 4 * BNODES; j += 256) h[j] = 0;
    for (int j = tid; j < sz; j += 256) buf[j] = edata[e0 + j];
    __syncthreads();
    for (int j = tid; j < sz; j += 256) {
        unsigned xx = buf[j].x;
        int key = (((xx >> 20) & 127) << 2) | (((xx >> 17) & 1) << 1) | ((xx >> 18) & 1);
        atomicAdd(&h[key], 1);
    }
    __syncthreads();
    int b0 = 0, b1 = 0, b2 = 0, b3 = 0;
    if (tid < BNODES) {
        b0 = h[4 * tid]; b1 = h[4 * tid + 1]; b2 = h[4 * tid + 2]; b3 = h[4 * tid + 3];
    }
    int tsum = b0 + b1 + b2 + b3;
    tp[tid] = tsum;
    __syncthreads();
    for (int d = 1; d < 256; d <<= 1) {
        int u = (tid >= d) ? tp[tid - d] : 0;
        __syncthreads();
        tp[tid] += u;
        __syncthreads();
    }
    int ebase = tp[tid] - tsum;
    if (tid < BNODES) {
        ex[4 * tid]     = ebase;
        ex[4 * tid + 1] = ebase + b0;
        ex[4 * tid + 2] = ebase + b0 + b1;
        ex[4 * tid + 3] = ebase + b0 + b1 + b2;
        int n = b * BNODES + tid;
        if (n < N_NODES) {
            nstart[n] = e0 + ebase;
            ncnt4[n] = make_uint2((unsigned)b0 | ((unsigned)b1 << 16),
                                  (unsigned)b2 | ((unsigned)b3 << 16));
        }
    }
    __syncthreads();
    for (int j = tid; j < sz; j += 256) {
        uint2 r = buf[j];
        unsigned xx = r.x;
        int key = (((xx >> 20) & 127) << 2) | (((xx >> 17) & 1) << 1) | ((xx >> 18) & 1);
        int p = atomicAdd(&ex[key], 1);
        float wa1f = (float)(r.y & 0xFFFF) * (1.f / 65535.f);
        float wb1f = (float)(r.y >> 16) * (1.f / 65535.f);
        unsigned wa1b = __float_as_uint(wa1f) >> 16;
        unsigned wb1b = __float_as_uint(wb1f) >> 16;
        uint2 outr;
        outr.x = (xx & 0x1FFFF) << 6;   // row * 64 bytes (bf16 row)
        outr.y = wa1b | (wb1b << 16);
        edata[e0 + p] = outr;
    }
}

// ---------------------------------------------------------------------------
// Fused gather + MFMA: block = 16 nodes, 4 waves x 4 nodes. z -> LDS only
// (10.5 KB); MFMA B-frags read from global Bg (L2-hot). Chunk-4 prefetch.
// Full 8 waves/SIMD occupancy.
// ---------------------------------------------------------------------------
__global__ __launch_bounds__(256, 8) void gather_mm_kernel(const bf16* __restrict__ xb,
                                                           const bf16* __restrict__ Bg,
                                                           const float* __restrict__ rb,
                                                           const int* __restrict__ nstart,
                                                           const uint2* __restrict__ ncnt4,
                                                           const uint2* __restrict__ edata,
                                                           float* __restrict__ out) {
    __shared__ __align__(16) bf16 zlds[16 * RS];   // 10496 B
    int tid = threadIdx.x;
    int wid = tid >> 6;
    int lane = tid & 63;
    int half = lane >> 5;
    int i = lane & 31;
    int ioff = i << 1;
    int n0 = blockIdx.x * 16;
    const char* xbb = (const char*)xb;

    for (int s = 0; s < 4; ++s) {
        int r = wid * 4 + s;
        int n = n0 + r;
        const uint2* ep = edata + nstart[n];
        uint2 cc = ncnt4[n];
        int c00 = cc.x & 0xFFFF, c01 = cc.x >> 16;
        int c10 = cc.y & 0xFFFF, c11 = cc.y >> 16;
        int dg = c00 + c01 + c10 + c11;

        float a0 = 0.f, a1 = 0.f, a2 = 0.f, a3 = 0.f, a4 = 0.f,
              a5 = 0.f, a6 = 0.f, a7 = 0.f, a8 = 0.f;

#define EDGE_FMA(ED, XV, A0, A1, A2, A3)                                 \
        {                                                                \
            float wa1v = __uint_as_float((ED).y << 16);                  \
            float wb1v = __uint_as_float((ED).y & 0xFFFF0000u);          \
            float wb0v = 1.f - wb1v;                                     \
            float t1 = wa1v * (XV);                                      \
            float t0 = (XV) - t1;                                        \
            A0 += t0 * wb0v;  A1 += t0 * wb1v;                           \
            A2 += t1 * wb0v;  A3 += t1 * wb1v;                           \
        }

#define XLOAD(ED) __bfloat162float(*(const bf16*)(xbb + (ED).x + ioff))

#define EDGE_RUN(CNT, A0, A1, A2, A3)                                    \
        {                                                                \
            int jb = half ? ((CNT) >> 1) : 0;                            \
            int je = half ? (CNT) : ((CNT) >> 1);                        \
            int j = jb;                                                  \
            for (; j + 3 < je; j += 4) {                                 \
                uint2 e0 = ep[j], e1 = ep[j + 1], e2 = ep[j + 2], e3 = ep[j + 3]; \
                float x0 = XLOAD(e0);                                    \
                float x1 = XLOAD(e1);                                    \
                float x2 = XLOAD(e2);                                    \
                float x3 = XLOAD(e3);                                    \
                EDGE_FMA(e0, x0, A0, A1, A2, A3)                         \
                EDGE_FMA(e1, x1, A0, A1, A2, A3)                         \
                EDGE_FMA(e2, x2, A0, A1, A2, A3)                         \
                EDGE_FMA(e3, x3, A0, A1, A2, A3)                         \
            }                                                            \
            for (; j < je; ++j) {                                        \
                uint2 e0 = ep[j];                                        \
                float x0 = XLOAD(e0);                                    \
                EDGE_FMA(e0, x0, A0, A1, A2, A3)                         \
            }                                                            \
            ep += (CNT);                                                 \
        }

        EDGE_RUN(c00, a0, a1, a3, a4)   // (ia,ib)=(0,0) -> planes 0,1,3,4
        EDGE_RUN(c01, a1, a2, a4, a5)   // (0,1) -> planes 1,2,4,5
        EDGE_RUN(c10, a3, a4, a6, a7)   // (1,0) -> planes 3,4,6,7
        EDGE_RUN(c11, a4, a5, a7, a8)   // (1,1) -> planes 4,5,7,8
#undef EDGE_RUN
#undef XLOAD
#undef EDGE_FMA

        a0 += __shfl_down(a0, 32); a1 += __shfl_down(a1, 32); a2 += __shfl_down(a2, 32);
        a3 += __shfl_down(a3, 32); a4 += __shfl_down(a4, 32); a5 += __shfl_down(a5, 32);
        a6 += __shfl_down(a6, 32); a7 += __shfl_down(a7, 32); a8 += __shfl_down(a8, 32);

        if (half == 0) {
            float inv = 1.f / fmaxf((float)dg, 1.f);
            bf16* zr = zlds + r * RS + i;
            zr[0 * CH] = __float2bfloat16(a0 * inv);
            zr[1 * CH] = __float2bfloat16(a1 * inv);
            zr[2 * CH] = __float2bfloat16(a2 * inv);
            zr[3 * CH] = __float2bfloat16(a3 * inv);
            zr[4 * CH] = __float2bfloat16(a4 * inv);
            zr[5 * CH] = __float2bfloat16(a5 * inv);
            zr[6 * CH] = __float2bfloat16(a6 * inv);
            zr[7 * CH] = __float2bfloat16(a7 * inv);
            zr[8 * CH] = __float2bfloat16(a8 * inv);
            zr[9 * CH] = xb[(size_t)n * CH + i];   // root plane
        }
    }
    __syncthreads();

    if (wid < 2) {   // wave 0 -> cols 0-15, wave 1 -> cols 16-31
        int lr = lane & 15, lq = lane >> 4;
        const bf16* brow = Bg + (size_t)(lr + wid * 16) * RS;
        f32x4 acc = {0.f, 0.f, 0.f, 0.f};
#pragma unroll
        for (int ks = 0; ks < 10; ++ks) {
            int kk = ks * 32 + lq * 8;
            bf16x8 a = *(const bf16x8*)(zlds + lr * RS + kk);
            bf16x8 b = *(const bf16x8*)(brow + kk);        // global, L2-hot
            acc = __builtin_amdgcn_mfma_f32_16x16x32_bf16(a, b, acc, 0, 0, 0);
        }
        float bias = rb[lr + wid * 16];
#pragma unroll
        for (int r = 0; r < 4; ++r) {
            int n = n0 + lq * 4 + r;
            out[(size_t)n * CH + lr + wid * 16] = acc[r] + bias;
        }
    }
}

// ---------------------------------------------------------------------------
extern "C" void kernel_launch(void* const* d_in, const int* in_sizes, int n_in,
                              void* d_out, int out_size, void* d_ws, size_t ws_size,
                              hipStream_t stream) {
    const float* x      = (const float*)d_in[0];
    const float* pseudo = (const float*)d_in[1];
    const float* weight = (const float*)d_in[2];
    const float* root_w = (const float*)d_in[3];
    const float* root_b = (const float*)d_in[4];
    const int*   ei     = (const int*)d_in[5];
    float* out = (float*)d_out;

    int* hist    = (int*)d_ws;                  // 1024 (NBUCK=782 used)
    int* bstart  = hist + 1024;                 // 1024 (NBUCK+1 used)
    int* cursor  = bstart + 1024;               // NBUCK*16 = 12512 (pad 12544)
    int* nstart  = cursor + 12544;              // 100032
    uint2* ncnt4 = (uint2*)(nstart + 100032);   // 100032 uint2
    char* basep  = (char*)(ncnt4 + 100032);
    size_t off   = ((size_t)(basep - (char*)d_ws) + 1023) & ~(size_t)1023;
    uint2* edata = (uint2*)((char*)d_ws + off);      // 25.6 MB
    bf16* xb     = (bf16*)(edata + N_EDGES);         // 6.4 MB
    bf16* Bg     = xb + (size_t)N_NODES * CH;        // 21 KB

    hipMemsetAsync(hist, 0, NBUCK * sizeof(int), stream);
    prep_kernel<<<(N_NODES * CH / 4 + 255) / 256, 256, 0, stream>>>(x, weight, root_w, xb, Bg);
    bhist_kernel<<<256, 256, 0, stream>>>(ei + N_EDGES, hist);
    bscan_kernel<<<1, 1024, 0, stream>>>(hist, bstart, cursor);
    place_kernel<<<NCHUNK, 256, 0, stream>>>(pseudo, ei, cursor, edata);
    bsort_kernel<<<NBUCK, 256, 0, stream>>>(bstart, edata, nstart, ncnt4);
    gather_mm_kernel<<<N_NODES / 16, 256, 0, stream>>>(xb, Bg, root_b, nstart, ncnt4,
                                                       edata, out);
}

// Round 12
// 240.293 us; speedup vs baseline: 1.3068x; 1.0329x over previous
//
#include <hip/hip_runtime.h>
#include <hip/hip_bf16.h>

#define N_NODES 100000
#define N_EDGES 3200000
#define CH 32
#define NK 9
#define KTOT 320                                // 288 z + 32 x (root plane)
#define RS 328                                  // padded K stride (bf16)

#define BNODES 128                              // destination nodes per bucket
#define NBUCK ((N_NODES + BNODES - 1) / BNODES) // 782
#define CURS_PAD 16
#define MAXB 4800                               // mean 4093, ~11 sigma margin
#define CHE 8192
#define NCHUNK ((N_EDGES + CHE - 1) / CHE)      // 391

typedef __hip_bfloat16 bf16;
typedef __attribute__((ext_vector_type(8))) short bf16x8;
typedef __attribute__((ext_vector_type(4))) float f32x4;

// ---------------------------------------------------------------------------
// Prep: x -> bf16 copy; [weight | root_w^T] -> bf16 B-matrix (MFMA row layout)
// ---------------------------------------------------------------------------
__global__ __launch_bounds__(256) void prep_kernel(const float* __restrict__ x,
                                                   const float* __restrict__ w,
                                                   const float* __restrict__ rw,
                                                   bf16* __restrict__ xb,
                                                   bf16* __restrict__ Bg) {
    int idx = blockIdx.x * 256 + threadIdx.x;
    if (idx < N_NODES * CH / 4) {
        float4 v = ((const float4*)x)[idx];
        union { bf16 h[4]; uint2 u; } pk;
        pk.h[0] = __float2bfloat16(v.x);
        pk.h[1] = __float2bfloat16(v.y);
        pk.h[2] = __float2bfloat16(v.z);
        pk.h[3] = __float2bfloat16(v.w);
        ((uint2*)xb)[idx] = pk.u;
    }
    if (idx < NK * CH * CH) {           // w flat = [k][i][o] = kk*32 + o
        int kk = idx >> 5, o = idx & 31;
        Bg[o * RS + kk] = __float2bfloat16(w[idx]);
    }
    if (idx < CH * CH) {                // rw[o][i]
        int o = idx >> 5, i = idx & 31;
        Bg[o * RS + 288 + i] = __float2bfloat16(rw[idx]);
    }
}

// ---------------------------------------------------------------------------
// Bucket histogram (global), int4-vectorized
// ---------------------------------------------------------------------------
__global__ __launch_bounds__(256) void bhist_kernel(const int* __restrict__ ei_col,
                                                    int* __restrict__ hist) {
    __shared__ int h[NBUCK];
    for (int j = threadIdx.x; j < NBUCK; j += 256) h[j] = 0;
    __syncthreads();
    const int4* c4 = (const int4*)ei_col;
    int stride = gridDim.x * 256;
    for (int e = blockIdx.x * 256 + threadIdx.x; e < N_EDGES / 4; e += stride) {
        int4 v = c4[e];
        atomicAdd(&h[v.x >> 7], 1);
        atomicAdd(&h[v.y >> 7], 1);
        atomicAdd(&h[v.z >> 7], 1);
        atomicAdd(&h[v.w >> 7], 1);
    }
    __syncthreads();
    for (int j = threadIdx.x; j < NBUCK; j += 256)
        if (h[j]) atomicAdd(&hist[j], h[j]);
}

// ---------------------------------------------------------------------------
// Single-block exclusive scan over buckets; writes bstart + sentinel + cursors
// ---------------------------------------------------------------------------
__global__ __launch_bounds__(1024) void bscan_kernel(const int* __restrict__ hist,
                                                     int* __restrict__ bstart,
                                                     int* __restrict__ cursor) {
    __shared__ int s[1024];
    int t = threadIdx.x;
    int a = (2 * t < NBUCK) ? hist[2 * t] : 0;
    int b = (2 * t + 1 < NBUCK) ? hist[2 * t + 1] : 0;
    s[t] = a + b;
    __syncthreads();
    for (int off = 1; off < 1024; off <<= 1) {
        int u = (t >= off) ? s[t - off] : 0;
        __syncthreads();
        s[t] += u;
        __syncthreads();
    }
    int excl = s[t] - (a + b);
    if (2 * t < NBUCK) {
        bstart[2 * t] = excl;
        cursor[2 * t * CURS_PAD] = excl;
    }
    if (2 * t + 1 < NBUCK) {
        bstart[2 * t + 1] = excl + a;
        cursor[(2 * t + 1) * CURS_PAD] = excl + a;
    }
    if (t == 1023) bstart[NBUCK] = s[1023];
}

// ---------------------------------------------------------------------------
// Place with per-block batch allocation; chunk cols cached in LDS (one read).
// Record: {row(17b)|ia(1)|ib(1)|lc(7b), qa|qb}
// ---------------------------------------------------------------------------
__global__ __launch_bounds__(256) void place_kernel(const float* __restrict__ pseudo,
                                                    const int* __restrict__ ei,
                                                    int* __restrict__ cursor,
                                                    uint2* __restrict__ edata) {
    __shared__ int h[NBUCK];
    __shared__ int gb[NBUCK];
    __shared__ int cols[CHE];   // 32 KB
    int tid = threadIdx.x;
    int c0 = blockIdx.x * CHE;
    int cend = min(c0 + CHE, N_EDGES);

    for (int j = tid; j < NBUCK; j += 256) h[j] = 0;
    __syncthreads();
    for (int e = c0 + tid; e < cend; e += 256) {
        int c = ei[N_EDGES + e];
        cols[e - c0] = c;
        atomicAdd(&h[c >> 7], 1);
    }
    __syncthreads();
    for (int j = tid; j < NBUCK; j += 256)
        gb[j] = h[j] ? atomicAdd(&cursor[j * CURS_PAD], h[j]) : 0;
    __syncthreads();

    for (int e = c0 + tid; e < cend; e += 256) {
        int col = cols[e - c0];
        int row = ei[e];
        float2 pp = ((const float2*)pseudo)[e];
        float pa = fminf(fmaxf(pp.x, 0.f), 1.f);
        float pb = fminf(fmaxf(pp.y, 0.f), 1.f);
        int ia = pa < 0.5f ? 0 : 1;
        int ib = pb < 0.5f ? 0 : 1;
        float wa1 = 2.f * (pa - 0.5f * (float)ia);
        float wb1 = 2.f * (pb - 0.5f * (float)ib);
        unsigned qa = (unsigned)(wa1 * 65535.f + 0.5f);
        unsigned qb = (unsigned)(wb1 * 65535.f + 0.5f);
        int pos = atomicAdd(&gb[col >> 7], 1);
        uint2 d;
        d.x = (unsigned)row | ((unsigned)ia << 17) | ((unsigned)ib << 18)
            | ((unsigned)(col & 127) << 20);
        d.y = qa | (qb << 16);
        edata[pos] = d;
    }
}

// ---------------------------------------------------------------------------
// Per-bucket counting sort by key=(lc,ia,ib) (512 classes). Output records:
// {row*64 (bf16-row byte off), wa1_bf16 | wb1_bf16<<16}; counts packed 4x u16.
// ---------------------------------------------------------------------------
__global__ __launch_bounds__(256) void bsort_kernel(const int* __restrict__ bstart,
                                                    uint2* __restrict__ edata,
                                                    int* __restrict__ nstart,
                                                    uint2* __restrict__ ncnt4) {
    __shared__ uint2 buf[MAXB];   // 38.4 KB
    __shared__ int h[4 * BNODES];   // 512 keys
    __shared__ int ex[4 * BNODES];
    __shared__ int tp[256];
    int tid = threadIdx.x;
    int b = blockIdx.x;
    int e0 = bstart[b], e1 = bstart[b + 1];
    int sz = min(e1 - e0, MAXB);

    for (int j = tid; j < 4 * BNODES; j += 256) h[j] = 0;
    for (int j = tid; j < sz; j += 256) buf[j] = edata[e0 + j];
    __syncthreads();
    for (int j = tid; j < sz; j += 256) {
        unsigned xx = buf[j].x;
        int key = (((xx >> 20) & 127) << 2) | (((xx >> 17) & 1) << 1) | ((xx >> 18) & 1);
        atomicAdd(&h[key], 1);
    }
    __syncthreads();
    int b0 = 0, b1 = 0, b2 = 0, b3 = 0;
    if (tid < BNODES) {
        b0 = h[4 * tid]; b1 = h[4 * tid + 1]; b2 = h[4 * tid + 2]; b3 = h[4 * tid + 3];
    }
    int tsum = b0 + b1 + b2 + b3;
    tp[tid] = tsum;
    __syncthreads();
    for (int d = 1; d < 256; d <<= 1) {
        int u = (tid >= d) ? tp[tid - d] : 0;
        __syncthreads();
        tp[tid] += u;
        __syncthreads();
    }
    int ebase = tp[tid] - tsum;
    if (tid < BNODES) {
        ex[4 * tid]     = ebase;
        ex[4 * tid + 1] = ebase + b0;
        ex[4 * tid + 2] = ebase + b0 + b1;
        ex[4 * tid + 3] = ebase + b0 + b1 + b2;
        int n = b * BNODES + tid;
        if (n < N_NODES) {
            nstart[n] = e0 + ebase;
            ncnt4[n] = make_uint2((unsigned)b0 | ((unsigned)b1 << 16),
                                  (unsigned)b2 | ((unsigned)b3 << 16));
        }
    }
    __syncthreads();
    for (int j = tid; j < sz; j += 256) {
        uint2 r = buf[j];
        unsigned xx = r.x;
        int key = (((xx >> 20) & 127) << 2) | (((xx >> 17) & 1) << 1) | ((xx >> 18) & 1);
        int p = atomicAdd(&ex[key], 1);
        float wa1f = (float)(r.y & 0xFFFF) * (1.f / 65535.f);
        float wb1f = (float)(r.y >> 16) * (1.f / 65535.f);
        unsigned wa1b = __float_as_uint(wa1f) >> 16;
        unsigned wb1b = __float_as_uint(wb1f) >> 16;
        uint2 outr;
        outr.x = (xx & 0x1FFFF) << 6;   // row * 64 bytes (bf16 row)
        outr.y = wa1b | (wb1b << 16);
        edata[e0 + p] = outr;
    }
}

// ---------------------------------------------------------------------------
// Fused gather + MFMA. Dual-stream class pairs: classes (00,01) and (10,11)
// processed simultaneously, chunk-4 per stream -> 8 independent x-loads in
// flight per half-wave. Validity via cndmask (weights word AND xv zeroed);
// over-reads land in the +8-record edata pad and a 16MB-masked x window.
// ---------------------------------------------------------------------------
__global__ __launch_bounds__(256, 6) void gather_mm_kernel(const bf16* __restrict__ xb,
                                                           const bf16* __restrict__ Bg,
                                                           const float* __restrict__ rb,
                                                           const int* __restrict__ nstart,
                                                           const uint2* __restrict__ ncnt4,
                                                           const uint2* __restrict__ edata,
                                                           float* __restrict__ out) {
    __shared__ __align__(16) bf16 zlds[16 * RS];   // 10496 B
    int tid = threadIdx.x;
    int wid = tid >> 6;
    int lane = tid & 63;
    int half = lane >> 5;
    int i = lane & 31;
    int ioff = i << 1;
    int n0 = blockIdx.x * 16;
    const char* xbb = (const char*)xb;

#define EDGE_FMA(EDY, XV, A0, A1, A2, A3)                                \
        {                                                                \
            float wa1v = __uint_as_float((EDY) << 16);                   \
            float wb1v = __uint_as_float((EDY) & 0xFFFF0000u);           \
            float wb0v = 1.f - wb1v;                                     \
            float t1 = wa1v * (XV);                                      \
            float t0 = (XV) - t1;                                        \
            A0 += t0 * wb0v;  A1 += t0 * wb1v;                           \
            A2 += t1 * wb0v;  A3 += t1 * wb1v;                           \
        }

#define XL(ED) __bfloat162float(*(const bf16*)(xbb + ((ED).x & 0xFFFFFFu) + ioff))

#define PAIR(CA, OA, CB, OB, A0, A1, A2, A3, T0, T1, T2, T3)             \
    {                                                                    \
        int jA = half ? ((CA) >> 1) : 0, jeA = half ? (CA) : ((CA) >> 1);\
        int jB = half ? ((CB) >> 1) : 0, jeB = half ? (CB) : ((CB) >> 1);\
        const uint2* epA = edata + s0 + (OA);                            \
        const uint2* epB = edata + s0 + (OB);                            \
        float q0 = 0.f, q1 = 0.f, q2 = 0.f, q3 = 0.f;                    \
        while (jA < jeA || jB < jeB) {                                   \
            uint2 eA0 = epA[jA],     eA1 = epA[jA + 1];                  \
            uint2 eA2 = epA[jA + 2], eA3 = epA[jA + 3];                  \
            uint2 eB0 = epB[jB],     eB1 = epB[jB + 1];                  \
            uint2 eB2 = epB[jB + 2], eB3 = epB[jB + 3];                  \
            float xA0 = XL(eA0), xA1 = XL(eA1), xA2 = XL(eA2), xA3 = XL(eA3); \
            float xB0 = XL(eB0), xB1 = XL(eB1), xB2 = XL(eB2), xB3 = XL(eB3); \
            bool vA0 = jA < jeA,     vA1 = jA + 1 < jeA;                 \
            bool vA2 = jA + 2 < jeA, vA3 = jA + 3 < jeA;                 \
            bool vB0 = jB < jeB,     vB1 = jB + 1 < jeB;                 \
            bool vB2 = jB + 2 < jeB, vB3 = jB + 3 < jeB;                 \
            unsigned yA0 = vA0 ? eA0.y : 0u;  xA0 = vA0 ? xA0 : 0.f;     \
            unsigned yA1 = vA1 ? eA1.y : 0u;  xA1 = vA1 ? xA1 : 0.f;     \
            unsigned yA2 = vA2 ? eA2.y : 0u;  xA2 = vA2 ? xA2 : 0.f;     \
            unsigned yA3 = vA3 ? eA3.y : 0u;  xA3 = vA3 ? xA3 : 0.f;     \
            unsigned yB0 = vB0 ? eB0.y : 0u;  xB0 = vB0 ? xB0 : 0.f;     \
            unsigned yB1 = vB1 ? eB1.y : 0u;  xB1 = vB1 ? xB1 : 0.f;     \
            unsigned yB2 = vB2 ? eB2.y : 0u;  xB2 = vB2 ? xB2 : 0.f;     \
            unsigned yB3 = vB3 ? eB3.y : 0u;  xB3 = vB3 ? xB3 : 0.f;     \
            EDGE_FMA(yA0, xA0, A0, A1, A2, A3)                           \
            EDGE_FMA(yA1, xA1, A0, A1, A2, A3)                           \
            EDGE_FMA(yA2, xA2, A0, A1, A2, A3)                           \
            EDGE_FMA(yA3, xA3, A0, A1, A2, A3)                           \
            EDGE_FMA(yB0, xB0, q0, q1, q2, q3)                           \
            EDGE_FMA(yB1, xB1, q0, q1, q2, q3)                           \
            EDGE_FMA(yB2, xB2, q0, q1, q2, q3)                           \
            EDGE_FMA(yB3, xB3, q0, q1, q2, q3)                           \
            jA += 4; jB += 4;                                            \
        }                                                                \
        T0 += q0; T1 += q1; T2 += q2; T3 += q3;                          \
    }

    for (int s = 0; s < 4; ++s) {
        int r = wid * 4 + s;
        int n = n0 + r;
        int s0 = nstart[n];
        uint2 cc = ncnt4[n];
        int c00 = cc.x & 0xFFFF, c01 = cc.x >> 16;
        int c10 = cc.y & 0xFFFF, c11 = cc.y >> 16;
        int dg = c00 + c01 + c10 + c11;
        int o01 = c00, o10 = c00 + c01, o11 = c00 + c01 + c10;

        float a0 = 0.f, a1 = 0.f, a2 = 0.f, a3 = 0.f, a4 = 0.f,
              a5 = 0.f, a6 = 0.f, a7 = 0.f, a8 = 0.f;

        // pair 1: class (0,0) -> planes {0,1,3,4};  class (0,1) -> {1,2,4,5}
        PAIR(c00, 0,   c01, o01, a0, a1, a3, a4, a1, a2, a4, a5)
        // pair 2: class (1,0) -> planes {3,4,6,7};  class (1,1) -> {4,5,7,8}
        PAIR(c10, o10, c11, o11, a3, a4, a6, a7, a4, a5, a7, a8)

        a0 += __shfl_down(a0, 32); a1 += __shfl_down(a1, 32); a2 += __shfl_down(a2, 32);
        a3 += __shfl_down(a3, 32); a4 += __shfl_down(a4, 32); a5 += __shfl_down(a5, 32);
        a6 += __shfl_down(a6, 32); a7 += __shfl_down(a7, 32); a8 += __shfl_down(a8, 32);

        if (half == 0) {
            float inv = 1.f / fmaxf((float)dg, 1.f);
            bf16* zr = zlds + r * RS + i;
            zr[0 * CH] = __float2bfloat16(a0 * inv);
            zr[1 * CH] = __float2bfloat16(a1 * inv);
            zr[2 * CH] = __float2bfloat16(a2 * inv);
            zr[3 * CH] = __float2bfloat16(a3 * inv);
            zr[4 * CH] = __float2bfloat16(a4 * inv);
            zr[5 * CH] = __float2bfloat16(a5 * inv);
            zr[6 * CH] = __float2bfloat16(a6 * inv);
            zr[7 * CH] = __float2bfloat16(a7 * inv);
            zr[8 * CH] = __float2bfloat16(a8 * inv);
            zr[9 * CH] = xb[(size_t)n * CH + i];   // root plane
        }
    }
#undef PAIR
#undef XL
#undef EDGE_FMA
    __syncthreads();

    if (wid < 2) {   // wave 0 -> cols 0-15, wave 1 -> cols 16-31
        int lr = lane & 15, lq = lane >> 4;
        const bf16* brow = Bg + (size_t)(lr + wid * 16) * RS;
        f32x4 acc = {0.f, 0.f, 0.f, 0.f};
#pragma unroll
        for (int ks = 0; ks < 10; ++ks) {
            int kk = ks * 32 + lq * 8;
            bf16x8 a = *(const bf16x8*)(zlds + lr * RS + kk);
            bf16x8 b = *(const bf16x8*)(brow + kk);        // global, L2-hot
            acc = __builtin_amdgcn_mfma_f32_16x16x32_bf16(a, b, acc, 0, 0, 0);
        }
        float bias = rb[lr + wid * 16];
#pragma unroll
        for (int r = 0; r < 4; ++r) {
            int n = n0 + lq * 4 + r;
            out[(size_t)n * CH + lr + wid * 16] = acc[r] + bias;
        }
    }
}

// ---------------------------------------------------------------------------
extern "C" void kernel_launch(void* const* d_in, const int* in_sizes, int n_in,
                              void* d_out, int out_size, void* d_ws, size_t ws_size,
                              hipStream_t stream) {
    const float* x      = (const float*)d_in[0];
    const float* pseudo = (const float*)d_in[1];
    const float* weight = (const float*)d_in[2];
    const float* root_w = (const float*)d_in[3];
    const float* root_b = (const float*)d_in[4];
    const int*   ei     = (const int*)d_in[5];
    float* out = (float*)d_out;

    int* hist    = (int*)d_ws;                  // 1024 (NBUCK=782 used)
    int* bstart  = hist + 1024;                 // 1024 (NBUCK+1 used)
    int* cursor  = bstart + 1024;               // NBUCK*16 = 12512 (pad 12544)
    int* nstart  = cursor + 12544;              // 100032
    uint2* ncnt4 = (uint2*)(nstart + 100032);   // 100032 uint2
    char* basep  = (char*)(ncnt4 + 100032);
    size_t off   = ((size_t)(basep - (char*)d_ws) + 1023) & ~(size_t)1023;
    uint2* edata = (uint2*)((char*)d_ws + off);      // 25.6 MB (+8 record pad)
    bf16* xb     = (bf16*)(edata + N_EDGES + 8);     // 6.4 MB
    bf16* Bg     = xb + (size_t)N_NODES * CH;        // 21 KB

    hipMemsetAsync(hist, 0, NBUCK * sizeof(int), stream);
    prep_kernel<<<(N_NODES * CH / 4 + 255) / 256, 256, 0, stream>>>(x, weight, root_w, xb, Bg);
    bhist_kernel<<<256, 256, 0, stream>>>(ei + N_EDGES, hist);
    bscan_kernel<<<1, 1024, 0, stream>>>(hist, bstart, cursor);
    place_kernel<<<NCHUNK, 256, 0, stream>>>(pseudo, ei, cursor, edata);
    bsort_kernel<<<NBUCK, 256, 0, stream>>>(bstart, edata, nstart, ncnt4);
    gather_mm_kernel<<<N_NODES / 16, 256, 0, stream>>>(xb, Bg, root_b, nstart, ncnt4,
                                                       edata, out);
}

// Round 13
// 177.814 us; speedup vs baseline: 1.7660x; 1.3514x over previous
//
#include <hip/hip_runtime.h>
#include <hip/hip_bf16.h>

#define N_NODES 100000
#define N_EDGES 3200000
#define CH 32
#define NK 9
#define KTOT 320                                // 288 z + 32 x (root plane)
#define RS 328                                  // padded K stride (bf16) for zlds

#define BNODES 128                              // destination nodes per bucket
#define NBUCK ((N_NODES + BNODES - 1) / BNODES) // 782
#define CURS_PAD 16
#define MAXB 4800                               // mean 4096, wide margin
#define CHE 8192
#define NCHUNK ((N_EDGES + CHE - 1) / CHE)      // 391

typedef __hip_bfloat16 bf16;
typedef unsigned short u16;
typedef __attribute__((ext_vector_type(8))) short bf16x8;
typedef __attribute__((ext_vector_type(4))) float f32x4;

// ---------------------------------------------------------------------------
// Prep: x -> bf16 copy; [weight | root_w^T] -> bf16 B-matrix (MFMA row layout)
// ---------------------------------------------------------------------------
__global__ __launch_bounds__(256) void prep_kernel(const float* __restrict__ x,
                                                   const float* __restrict__ w,
                                                   const float* __restrict__ rw,
                                                   bf16* __restrict__ xb,
                                                   bf16* __restrict__ Bg) {
    int idx = blockIdx.x * 256 + threadIdx.x;
    if (idx < N_NODES * CH / 4) {
        float4 v = ((const float4*)x)[idx];
        union { bf16 h[4]; uint2 u; } pk;
        pk.h[0] = __float2bfloat16(v.x);
        pk.h[1] = __float2bfloat16(v.y);
        pk.h[2] = __float2bfloat16(v.z);
        pk.h[3] = __float2bfloat16(v.w);
        ((uint2*)xb)[idx] = pk.u;
    }
    if (idx < NK * CH * CH) {           // w flat = [k][i][o] = kk*32 + o
        int kk = idx >> 5, o = idx & 31;
        Bg[o * RS + kk] = __float2bfloat16(w[idx]);
    }
    if (idx < CH * CH) {                // rw[o][i]
        int o = idx >> 5, i = idx & 31;
        Bg[o * RS + 288 + i] = __float2bfloat16(rw[idx]);
    }
}

// ---------------------------------------------------------------------------
// Bucket histogram (global), int4-vectorized
// ---------------------------------------------------------------------------
__global__ __launch_bounds__(256) void bhist_kernel(const int* __restrict__ ei_col,
                                                    int* __restrict__ hist) {
    __shared__ int h[NBUCK];
    for (int j = threadIdx.x; j < NBUCK; j += 256) h[j] = 0;
    __syncthreads();
    const int4* c4 = (const int4*)ei_col;
    int stride = gridDim.x * 256;
    for (int e = blockIdx.x * 256 + threadIdx.x; e < N_EDGES / 4; e += stride) {
        int4 v = c4[e];
        atomicAdd(&h[v.x >> 7], 1);
        atomicAdd(&h[v.y >> 7], 1);
        atomicAdd(&h[v.z >> 7], 1);
        atomicAdd(&h[v.w >> 7], 1);
    }
    __syncthreads();
    for (int j = threadIdx.x; j < NBUCK; j += 256)
        if (h[j]) atomicAdd(&hist[j], h[j]);
}

// ---------------------------------------------------------------------------
// Single-block exclusive scan over buckets; writes bstart + sentinel + cursors
// ---------------------------------------------------------------------------
__global__ __launch_bounds__(1024) void bscan_kernel(const int* __restrict__ hist,
                                                     int* __restrict__ bstart,
                                                     int* __restrict__ cursor) {
    __shared__ int s[1024];
    int t = threadIdx.x;
    int a = (2 * t < NBUCK) ? hist[2 * t] : 0;
    int b = (2 * t + 1 < NBUCK) ? hist[2 * t + 1] : 0;
    s[t] = a + b;
    __syncthreads();
    for (int off = 1; off < 1024; off <<= 1) {
        int u = (t >= off) ? s[t - off] : 0;
        __syncthreads();
        s[t] += u;
        __syncthreads();
    }
    int excl = s[t] - (a + b);
    if (2 * t < NBUCK) {
        bstart[2 * t] = excl;
        cursor[2 * t * CURS_PAD] = excl;
    }
    if (2 * t + 1 < NBUCK) {
        bstart[2 * t + 1] = excl + a;
        cursor[(2 * t + 1) * CURS_PAD] = excl + a;
    }
    if (t == 1023) bstart[NBUCK] = s[1023];
}

// ---------------------------------------------------------------------------
// Place with per-block batch allocation; chunk cols cached in LDS.
// Record: {row(17b)|ia(17)|ib(18)|lc(20-26), qa|qb}
// ---------------------------------------------------------------------------
__global__ __launch_bounds__(256) void place_kernel(const float* __restrict__ pseudo,
                                                    const int* __restrict__ ei,
                                                    int* __restrict__ cursor,
                                                    uint2* __restrict__ edata) {
    __shared__ int h[NBUCK];
    __shared__ int gb[NBUCK];
    __shared__ int cols[CHE];   // 32 KB
    int tid = threadIdx.x;
    int c0 = blockIdx.x * CHE;
    int cend = min(c0 + CHE, N_EDGES);

    for (int j = tid; j < NBUCK; j += 256) h[j] = 0;
    __syncthreads();
    for (int e = c0 + tid; e < cend; e += 256) {
        int c = ei[N_EDGES + e];
        cols[e - c0] = c;
        atomicAdd(&h[c >> 7], 1);
    }
    __syncthreads();
    for (int j = tid; j < NBUCK; j += 256)
        gb[j] = h[j] ? atomicAdd(&cursor[j * CURS_PAD], h[j]) : 0;
    __syncthreads();

    for (int e = c0 + tid; e < cend; e += 256) {
        int col = cols[e - c0];
        int row = ei[e];
        float2 pp = ((const float2*)pseudo)[e];
        float pa = fminf(fmaxf(pp.x, 0.f), 1.f);
        float pb = fminf(fmaxf(pp.y, 0.f), 1.f);
        int ia = pa < 0.5f ? 0 : 1;
        int ib = pb < 0.5f ? 0 : 1;
        float wa1 = 2.f * (pa - 0.5f * (float)ia);
        float wb1 = 2.f * (pb - 0.5f * (float)ib);
        unsigned qa = (unsigned)(wa1 * 65535.f + 0.5f);
        unsigned qb = (unsigned)(wb1 * 65535.f + 0.5f);
        int pos = atomicAdd(&gb[col >> 7], 1);
        uint2 d;
        d.x = (unsigned)row | ((unsigned)ia << 17) | ((unsigned)ib << 18)
            | ((unsigned)(col & 127) << 20);
        d.y = qa | (qb << 16);
        edata[pos] = d;
    }
}

// ---------------------------------------------------------------------------
// Per-bucket counting sort by node only (128 keys). Output record:
// {row*64 | ia<<30 | ib<<31, wa1_bf16 | wb1_bf16<<16}; ncnt plain int.
// ---------------------------------------------------------------------------
__global__ __launch_bounds__(256) void bsort_kernel(const int* __restrict__ bstart,
                                                    uint2* __restrict__ edata,
                                                    int* __restrict__ nstart,
                                                    int* __restrict__ ncnt) {
    __shared__ uint2 buf[MAXB];   // 38.4 KB
    __shared__ int h[BNODES];
    __shared__ int cur[BNODES];
    __shared__ int tp[256];
    int tid = threadIdx.x;
    int b = blockIdx.x;
    int e0 = bstart[b], e1 = bstart[b + 1];
    int sz = min(e1 - e0, MAXB);

    if (tid < BNODES) h[tid] = 0;
    for (int j = tid; j < sz; j += 256) buf[j] = edata[e0 + j];
    __syncthreads();
    for (int j = tid; j < sz; j += 256)
        atomicAdd(&h[(buf[j].x >> 20) & 127], 1);
    __syncthreads();
    int v = (tid < BNODES) ? h[tid] : 0;
    tp[tid] = v;
    __syncthreads();
    for (int d = 1; d < 256; d <<= 1) {
        int u = (tid >= d) ? tp[tid - d] : 0;
        __syncthreads();
        tp[tid] += u;
        __syncthreads();
    }
    int excl = tp[tid] - v;
    if (tid < BNODES) {
        cur[tid] = excl;
        int n = b * BNODES + tid;
        if (n < N_NODES) { nstart[n] = e0 + excl; ncnt[n] = v; }
    }
    __syncthreads();
    for (int j = tid; j < sz; j += 256) {
        uint2 r = buf[j];
        unsigned xx = r.x;
        int key = (xx >> 20) & 127;
        int p = atomicAdd(&cur[key], 1);
        float wa1f = (float)(r.y & 0xFFFF) * (1.f / 65535.f);
        float wb1f = (float)(r.y >> 16) * (1.f / 65535.f);
        unsigned wa1b = __float_as_uint(wa1f) >> 16;
        unsigned wb1b = __float_as_uint(wb1f) >> 16;
        uint2 outr;
        outr.x = ((xx & 0x1FFFF) << 6)               // row * 64 bytes
               | ((xx & (1u << 17)) << 13)           // ia -> bit 30
               | ((xx & (1u << 18)) << 13);          // ib -> bit 31
        outr.y = wa1b | (wb1b << 16);
        edata[e0 + p] = outr;
    }
}

// ---------------------------------------------------------------------------
// Fused gather via MFMA: per node, K-loop over 32-edge groups.
// A = coeff tile [16 planes][32 edges] (LDS, wave-private, planes 9-15 = 0),
// B = X^T tile [32 ch][32 edges] (LDS, wave-private), D[plane][ch] in AGPRs.
// Then Z -> zlds rows, and the verified 16x320x32 output MFMA phase.
// ---------------------------------------------------------------------------
__global__ __launch_bounds__(256, 6) void gather_mm_kernel(const bf16* __restrict__ xb,
                                                           const bf16* __restrict__ Bg,
                                                           const float* __restrict__ rb,
                                                           const int* __restrict__ nstart,
                                                           const int* __restrict__ ncnt,
                                                           const uint2* __restrict__ edata,
                                                           float* __restrict__ out) {
    __shared__ __align__(16) bf16 zlds[16 * RS];       // 10496 B
    __shared__ __align__(16) bf16 coef[4][16 * 40];    // 4 x 1280 B (stride 80 B)
    __shared__ __align__(16) bf16 xt[4][32 * 36];      // 4 x 2304 B (stride 72 B)
    int tid = threadIdx.x;
    int wid = tid >> 6;
    int lane = tid & 63;
    int lr = lane & 15, lg = lane >> 4;
    int e31 = lane & 31;
    int n0 = blockIdx.x * 16;
    const char* xbb = (const char*)xb;

    bf16* coefW = coef[wid];
    u16* xtU = (u16*)xt[wid];

    {   // zero coeff tile once (planes 9-15 + pad cols stay 0 forever)
        int* cz = (int*)coefW;
        for (int j = lane; j < 16 * 40 / 2; j += 64) cz[j] = 0;
    }

    for (int s = 0; s < 4; ++s) {
        int rr = wid * 4 + s;
        int n = n0 + rr;
        int s0 = nstart[n];
        int dg = ncnt[n];
        f32x4 accL = {0.f, 0.f, 0.f, 0.f};
        f32x4 accH = {0.f, 0.f, 0.f, 0.f};
        int ng = (dg + 31) >> 5;

        for (int g = 0; g < ng; ++g) {
            uint2 rec = edata[s0 + g * 32 + e31];     // lanes 32-63 duplicate
            bool valid = (g * 32 + e31) < dg;
            float wa1 = __uint_as_float(rec.y << 16);
            float wb1 = __uint_as_float(rec.y & 0xFFFF0000u);
            wa1 = valid ? wa1 : 0.f;                  // NaN-safe
            wb1 = valid ? wb1 : 0.f;
            float wa0 = 1.f - wa1, wb0 = 1.f - wb1;
            unsigned rx = rec.x;
            int ia = (rx >> 30) & 1;
            int ib = (rx >> 31) & 1;
            float A0 = ia ? 0.f : wa0, A1 = ia ? wa0 : wa1, A2 = ia ? wa1 : 0.f;
            float B0 = ib ? 0.f : wb0, B1 = ib ? wb0 : wb1, B2 = ib ? wb1 : 0.f;
            A0 = valid ? A0 : 0.f;                    // zero-coeff for pad edges
            A1 = valid ? A1 : 0.f;
            A2 = valid ? A2 : 0.f;
            int ro = valid ? (int)(rx & 0x00FFFFC0u) : 0;  // clamp pad to row 0

            if (lane < 32) {                          // A tile [plane][edge]
                coefW[0 * 40 + e31] = __float2bfloat16(A0 * B0);
                coefW[1 * 40 + e31] = __float2bfloat16(A0 * B1);
                coefW[2 * 40 + e31] = __float2bfloat16(A0 * B2);
                coefW[3 * 40 + e31] = __float2bfloat16(A1 * B0);
                coefW[4 * 40 + e31] = __float2bfloat16(A1 * B1);
                coefW[5 * 40 + e31] = __float2bfloat16(A1 * B2);
                coefW[6 * 40 + e31] = __float2bfloat16(A2 * B0);
                coefW[7 * 40 + e31] = __float2bfloat16(A2 * B1);
                coefW[8 * 40 + e31] = __float2bfloat16(A2 * B2);
            }

            int rem = dg - g * 32;
#pragma unroll
            for (int t = 0; t < 2; ++t) {             // stage 32 x-rows -> X^T
                int e = 16 * t + (lane >> 2);
                int roe = __shfl(ro, e);
                uint4 v = *(const uint4*)(xbb + roe + (lane & 3) * 16);
                bool vx = e < rem;
                v.x = vx ? v.x : 0u;                  // NaN-safe pad rows
                v.y = vx ? v.y : 0u;
                v.z = vx ? v.z : 0u;
                v.w = vx ? v.w : 0u;
                int c0 = (lane & 3) * 8;
                xtU[(c0 + 0) * 36 + e] = (u16)(v.x);
                xtU[(c0 + 1) * 36 + e] = (u16)(v.x >> 16);
                xtU[(c0 + 2) * 36 + e] = (u16)(v.y);
                xtU[(c0 + 3) * 36 + e] = (u16)(v.y >> 16);
                xtU[(c0 + 4) * 36 + e] = (u16)(v.z);
                xtU[(c0 + 5) * 36 + e] = (u16)(v.z >> 16);
                xtU[(c0 + 6) * 36 + e] = (u16)(v.w);
                xtU[(c0 + 7) * 36 + e] = (u16)(v.w >> 16);
            }

            // A-frag: lane(row=lr plane, k=8*lg+j) -> contiguous 16B
            bf16x8 af = *(const bf16x8*)(coefW + lr * 40 + lg * 8);
            // B-frags: lane(col=ch, k=8*lg+j) from X^T rows ch / ch+16
            const uint2* xlo = (const uint2*)((const char*)xtU + lr * 72 + lg * 16);
            const uint2* xhi = (const uint2*)((const char*)xtU + (lr + 16) * 72 + lg * 16);
            uint2 l0 = xlo[0], l1 = xlo[1];
            uint2 h0 = xhi[0], h1 = xhi[1];
            union UB { unsigned w[4]; bf16x8 v; } bl, bh;
            bl.w[0] = l0.x; bl.w[1] = l0.y; bl.w[2] = l1.x; bl.w[3] = l1.y;
            bh.w[0] = h0.x; bh.w[1] = h0.y; bh.w[2] = h1.x; bh.w[3] = h1.y;
            accL = __builtin_amdgcn_mfma_f32_16x16x32_bf16(af, bl.v, accL, 0, 0, 0);
            accH = __builtin_amdgcn_mfma_f32_16x16x32_bf16(af, bh.v, accH, 0, 0, 0);
        }

        float inv = 1.f / fmaxf((float)dg, 1.f);
#pragma unroll
        for (int r = 0; r < 4; ++r) {                 // C: col=lr, row=lg*4+r
            int p = lg * 4 + r;
            if (p < 9) {
                zlds[rr * RS + p * 32 + lr]      = __float2bfloat16(accL[r] * inv);
                zlds[rr * RS + p * 32 + lr + 16] = __float2bfloat16(accH[r] * inv);
            }
        }
        if (lane < CH) zlds[rr * RS + 288 + lane] = xb[(size_t)n * CH + lane];
    }
    __syncthreads();

    if (wid < 2) {   // wave 0 -> cols 0-15, wave 1 -> cols 16-31
        const bf16* brow = Bg + (size_t)(lr + wid * 16) * RS;
        f32x4 acc = {0.f, 0.f, 0.f, 0.f};
#pragma unroll
        for (int ks = 0; ks < 10; ++ks) {
            int kk = ks * 32 + lg * 8;
            bf16x8 a = *(const bf16x8*)(zlds + lr * RS + kk);
            bf16x8 b = *(const bf16x8*)(brow + kk);        // global, L2-hot
            acc = __builtin_amdgcn_mfma_f32_16x16x32_bf16(a, b, acc, 0, 0, 0);
        }
        float bias = rb[lr + wid * 16];
#pragma unroll
        for (int r = 0; r < 4; ++r) {
            int n = n0 + lg * 4 + r;
            out[(size_t)n * CH + lr + wid * 16] = acc[r] + bias;
        }
    }
}

// ---------------------------------------------------------------------------
extern "C" void kernel_launch(void* const* d_in, const int* in_sizes, int n_in,
                              void* d_out, int out_size, void* d_ws, size_t ws_size,
                              hipStream_t stream) {
    const float* x      = (const float*)d_in[0];
    const float* pseudo = (const float*)d_in[1];
    const float* weight = (const float*)d_in[2];
    const float* root_w = (const float*)d_in[3];
    const float* root_b = (const float*)d_in[4];
    const int*   ei     = (const int*)d_in[5];
    float* out = (float*)d_out;

    int* hist    = (int*)d_ws;                  // 1024 (NBUCK=782 used)
    int* bstart  = hist + 1024;                 // 1024 (NBUCK+1 used)
    int* cursor  = bstart + 1024;               // NBUCK*16 = 12512 (pad 12544)
    int* nstart  = cursor + 12544;              // 100032
    int* ncnt    = nstart + 100032;             // 100032
    char* basep  = (char*)(ncnt + 100032);
    size_t off   = ((size_t)(basep - (char*)d_ws) + 1023) & ~(size_t)1023;
    uint2* edata = (uint2*)((char*)d_ws + off);      // 25.6 MB (+64 record pad)
    bf16* xb     = (bf16*)(edata + N_EDGES + 64);    // 6.4 MB
    bf16* Bg     = xb + (size_t)N_NODES * CH;        // 21 KB

    hipMemsetAsync(hist, 0, NBUCK * sizeof(int), stream);
    prep_kernel<<<(N_NODES * CH / 4 + 255) / 256, 256, 0, stream>>>(x, weight, root_w, xb, Bg);
    bhist_kernel<<<256, 256, 0, stream>>>(ei + N_EDGES, hist);
    bscan_kernel<<<1, 1024, 0, stream>>>(hist, bstart, cursor);
    place_kernel<<<NCHUNK, 256, 0, stream>>>(pseudo, ei, cursor, edata);
    bsort_kernel<<<NBUCK, 256, 0, stream>>>(bstart, edata, nstart, ncnt);
    gather_mm_kernel<<<N_NODES / 16, 256, 0, stream>>>(xb, Bg, root_b, nstart, ncnt,
                                                       edata, out);
}

// Round 14
// 175.824 us; speedup vs baseline: 1.7859x; 1.0113x over previous
//
#include <hip/hip_runtime.h>
#include <hip/hip_bf16.h>

#define N_NODES 100000
#define N_EDGES 3200000
#define CH 32
#define NK 9
#define KTOT 320                                // 288 z + 32 x (root plane)
#define RS 328                                  // padded K stride (bf16) for zlds

#define BNODES 128                              // destination nodes per bucket
#define NBUCK ((N_NODES + BNODES - 1) / BNODES) // 782
#define CURS_PAD 16
#define MAXB 4800                               // mean 4096, wide margin
#define CHE 12288
#define NCHUNK ((N_EDGES + CHE - 1) / CHE)      // 261

typedef __hip_bfloat16 bf16;
typedef unsigned short u16;
typedef __attribute__((ext_vector_type(8))) short bf16x8;
typedef __attribute__((ext_vector_type(4))) float f32x4;

// ---------------------------------------------------------------------------
// Prep: x -> bf16 copy; [weight | root_w^T] -> bf16 B-matrix (MFMA row layout)
// ---------------------------------------------------------------------------
__global__ __launch_bounds__(256) void prep_kernel(const float* __restrict__ x,
                                                   const float* __restrict__ w,
                                                   const float* __restrict__ rw,
                                                   bf16* __restrict__ xb,
                                                   bf16* __restrict__ Bg) {
    int idx = blockIdx.x * 256 + threadIdx.x;
    if (idx < N_NODES * CH / 4) {
        float4 v = ((const float4*)x)[idx];
        union { bf16 h[4]; uint2 u; } pk;
        pk.h[0] = __float2bfloat16(v.x);
        pk.h[1] = __float2bfloat16(v.y);
        pk.h[2] = __float2bfloat16(v.z);
        pk.h[3] = __float2bfloat16(v.w);
        ((uint2*)xb)[idx] = pk.u;
    }
    if (idx < NK * CH * CH) {           // w flat = [k][i][o] = kk*32 + o
        int kk = idx >> 5, o = idx & 31;
        Bg[o * RS + kk] = __float2bfloat16(w[idx]);
    }
    if (idx < CH * CH) {                // rw[o][i]
        int o = idx >> 5, i = idx & 31;
        Bg[o * RS + 288 + i] = __float2bfloat16(rw[idx]);
    }
}

// ---------------------------------------------------------------------------
// Bucket histogram (global), int4-vectorized
// ---------------------------------------------------------------------------
__global__ __launch_bounds__(256) void bhist_kernel(const int* __restrict__ ei_col,
                                                    int* __restrict__ hist) {
    __shared__ int h[NBUCK];
    for (int j = threadIdx.x; j < NBUCK; j += 256) h[j] = 0;
    __syncthreads();
    const int4* c4 = (const int4*)ei_col;
    int stride = gridDim.x * 256;
    for (int e = blockIdx.x * 256 + threadIdx.x; e < N_EDGES / 4; e += stride) {
        int4 v = c4[e];
        atomicAdd(&h[v.x >> 7], 1);
        atomicAdd(&h[v.y >> 7], 1);
        atomicAdd(&h[v.z >> 7], 1);
        atomicAdd(&h[v.w >> 7], 1);
    }
    __syncthreads();
    for (int j = threadIdx.x; j < NBUCK; j += 256)
        if (h[j]) atomicAdd(&hist[j], h[j]);
}

// ---------------------------------------------------------------------------
// Single-block exclusive scan over buckets; writes bstart + sentinel + cursors
// ---------------------------------------------------------------------------
__global__ __launch_bounds__(1024) void bscan_kernel(const int* __restrict__ hist,
                                                     int* __restrict__ bstart,
                                                     int* __restrict__ cursor) {
    __shared__ int s[1024];
    int t = threadIdx.x;
    int a = (2 * t < NBUCK) ? hist[2 * t] : 0;
    int b = (2 * t + 1 < NBUCK) ? hist[2 * t + 1] : 0;
    s[t] = a + b;
    __syncthreads();
    for (int off = 1; off < 1024; off <<= 1) {
        int u = (t >= off) ? s[t - off] : 0;
        __syncthreads();
        s[t] += u;
        __syncthreads();
    }
    int excl = s[t] - (a + b);
    if (2 * t < NBUCK) {
        bstart[2 * t] = excl;
        cursor[2 * t * CURS_PAD] = excl;
    }
    if (2 * t + 1 < NBUCK) {
        bstart[2 * t + 1] = excl + a;
        cursor[(2 * t + 1) * CURS_PAD] = excl + a;
    }
    if (t == 1023) bstart[NBUCK] = s[1023];
}

// ---------------------------------------------------------------------------
// Place with per-block batch allocation; 1024-thread blocks for occupancy.
// Record: {row(17b)|ia(17)|ib(18)|lc(20-26), qa|qb}
// ---------------------------------------------------------------------------
__global__ __launch_bounds__(1024) void place_kernel(const float* __restrict__ pseudo,
                                                     const int* __restrict__ ei,
                                                     int* __restrict__ cursor,
                                                     uint2* __restrict__ edata) {
    __shared__ int h[NBUCK];
    __shared__ int gb[NBUCK];
    __shared__ int cols[CHE];   // 48 KB
    int tid = threadIdx.x;
    int c0 = blockIdx.x * CHE;
    int cend = min(c0 + CHE, N_EDGES);

    for (int j = tid; j < NBUCK; j += 1024) h[j] = 0;
    __syncthreads();
    for (int e = c0 + tid; e < cend; e += 1024) {
        int c = ei[N_EDGES + e];
        cols[e - c0] = c;
        atomicAdd(&h[c >> 7], 1);
    }
    __syncthreads();
    for (int j = tid; j < NBUCK; j += 1024)
        gb[j] = h[j] ? atomicAdd(&cursor[j * CURS_PAD], h[j]) : 0;
    __syncthreads();

    for (int e = c0 + tid; e < cend; e += 1024) {
        int col = cols[e - c0];
        int row = ei[e];
        float2 pp = ((const float2*)pseudo)[e];
        float pa = fminf(fmaxf(pp.x, 0.f), 1.f);
        float pb = fminf(fmaxf(pp.y, 0.f), 1.f);
        int ia = pa < 0.5f ? 0 : 1;
        int ib = pb < 0.5f ? 0 : 1;
        float wa1 = 2.f * (pa - 0.5f * (float)ia);
        float wb1 = 2.f * (pb - 0.5f * (float)ib);
        unsigned qa = (unsigned)(wa1 * 65535.f + 0.5f);
        unsigned qb = (unsigned)(wb1 * 65535.f + 0.5f);
        int pos = atomicAdd(&gb[col >> 7], 1);
        uint2 d;
        d.x = (unsigned)row | ((unsigned)ia << 17) | ((unsigned)ib << 18)
            | ((unsigned)(col & 127) << 20);
        d.y = qa | (qb << 16);
        edata[pos] = d;
    }
}

// ---------------------------------------------------------------------------
// Per-bucket counting sort by node only (128 keys). Output record:
// {row*64 | ia<<30 | ib<<31, wa1_bf16 | wb1_bf16<<16}; ncnt plain int.
// ---------------------------------------------------------------------------
__global__ __launch_bounds__(256) void bsort_kernel(const int* __restrict__ bstart,
                                                    uint2* __restrict__ edata,
                                                    int* __restrict__ nstart,
                                                    int* __restrict__ ncnt) {
    __shared__ uint2 buf[MAXB];   // 38.4 KB
    __shared__ int h[BNODES];
    __shared__ int cur[BNODES];
    __shared__ int tp[256];
    int tid = threadIdx.x;
    int b = blockIdx.x;
    int e0 = bstart[b], e1 = bstart[b + 1];
    int sz = min(e1 - e0, MAXB);

    if (tid < BNODES) h[tid] = 0;
    for (int j = tid; j < sz; j += 256) buf[j] = edata[e0 + j];
    __syncthreads();
    for (int j = tid; j < sz; j += 256)
        atomicAdd(&h[(buf[j].x >> 20) & 127], 1);
    __syncthreads();
    int v = (tid < BNODES) ? h[tid] : 0;
    tp[tid] = v;
    __syncthreads();
    for (int d = 1; d < 256; d <<= 1) {
        int u = (tid >= d) ? tp[tid - d] : 0;
        __syncthreads();
        tp[tid] += u;
        __syncthreads();
    }
    int excl = tp[tid] - v;
    if (tid < BNODES) {
        cur[tid] = excl;
        int n = b * BNODES + tid;
        if (n < N_NODES) { nstart[n] = e0 + excl; ncnt[n] = v; }
    }
    __syncthreads();
    for (int j = tid; j < sz; j += 256) {
        uint2 r = buf[j];
        unsigned xx = r.x;
        int key = (xx >> 20) & 127;
        int p = atomicAdd(&cur[key], 1);
        float wa1f = (float)(r.y & 0xFFFF) * (1.f / 65535.f);
        float wb1f = (float)(r.y >> 16) * (1.f / 65535.f);
        unsigned wa1b = __float_as_uint(wa1f) >> 16;
        unsigned wb1b = __float_as_uint(wb1f) >> 16;
        uint2 outr;
        outr.x = ((xx & 0x1FFFF) << 6)               // row * 64 bytes
               | ((xx & (1u << 17)) << 13)           // ia -> bit 30
               | ((xx & (1u << 18)) << 13);          // ib -> bit 31
        outr.y = wa1b | (wb1b << 16);
        edata[e0 + p] = outr;
    }
}

// ---------------------------------------------------------------------------
// Fused gather via MFMA: per node, K-loop over 32-edge groups.
// A = coeff tile [16 planes][32 edges] (LDS, wave-private, planes 9-15 = 0),
// B = X^T tile [32 ch][32 edges] (LDS, wave-private), D[plane][ch] in AGPRs.
// Then Z -> zlds rows, and the verified 16x320x32 output MFMA phase.
// ---------------------------------------------------------------------------
__global__ __launch_bounds__(256, 6) void gather_mm_kernel(const bf16* __restrict__ xb,
                                                           const bf16* __restrict__ Bg,
                                                           const float* __restrict__ rb,
                                                           const int* __restrict__ nstart,
                                                           const int* __restrict__ ncnt,
                                                           const uint2* __restrict__ edata,
                                                           float* __restrict__ out) {
    __shared__ __align__(16) bf16 zlds[16 * RS];       // 10496 B
    __shared__ __align__(16) bf16 coef[4][16 * 40];    // 4 x 1280 B (stride 80 B)
    __shared__ __align__(16) bf16 xt[4][32 * 36];      // 4 x 2304 B (stride 72 B)
    int tid = threadIdx.x;
    int wid = tid >> 6;
    int lane = tid & 63;
    int lr = lane & 15, lg = lane >> 4;
    int e31 = lane & 31;
    int n0 = blockIdx.x * 16;
    const char* xbb = (const char*)xb;

    bf16* coefW = coef[wid];
    u16* xtU = (u16*)xt[wid];

    {   // zero coeff tile once (planes 9-15 + pad cols stay 0 forever)
        int* cz = (int*)coefW;
        for (int j = lane; j < 16 * 40 / 2; j += 64) cz[j] = 0;
    }

    for (int s = 0; s < 4; ++s) {
        int rr = wid * 4 + s;
        int n = n0 + rr;
        int s0 = nstart[n];
        int dg = ncnt[n];
        f32x4 accL = {0.f, 0.f, 0.f, 0.f};
        f32x4 accH = {0.f, 0.f, 0.f, 0.f};
        int ng = (dg + 31) >> 5;

        for (int g = 0; g < ng; ++g) {
            uint2 rec = edata[s0 + g * 32 + e31];     // lanes 32-63 duplicate
            bool valid = (g * 32 + e31) < dg;
            float wa1 = __uint_as_float(rec.y << 16);
            float wb1 = __uint_as_float(rec.y & 0xFFFF0000u);
            wa1 = valid ? wa1 : 0.f;                  // NaN-safe
            wb1 = valid ? wb1 : 0.f;
            float wa0 = 1.f - wa1, wb0 = 1.f - wb1;
            unsigned rx = rec.x;
            int ia = (rx >> 30) & 1;
            int ib = (rx >> 31) & 1;
            float A0 = ia ? 0.f : wa0, A1 = ia ? wa0 : wa1, A2 = ia ? wa1 : 0.f;
            float B0 = ib ? 0.f : wb0, B1 = ib ? wb0 : wb1, B2 = ib ? wb1 : 0.f;
            A0 = valid ? A0 : 0.f;                    // zero-coeff for pad edges
            A1 = valid ? A1 : 0.f;
            A2 = valid ? A2 : 0.f;
            int ro = valid ? (int)(rx & 0x00FFFFC0u) : 0;  // clamp pad to row 0

            if (lane < 32) {                          // A tile [plane][edge]
                coefW[0 * 40 + e31] = __float2bfloat16(A0 * B0);
                coefW[1 * 40 + e31] = __float2bfloat16(A0 * B1);
                coefW[2 * 40 + e31] = __float2bfloat16(A0 * B2);
                coefW[3 * 40 + e31] = __float2bfloat16(A1 * B0);
                coefW[4 * 40 + e31] = __float2bfloat16(A1 * B1);
                coefW[5 * 40 + e31] = __float2bfloat16(A1 * B2);
                coefW[6 * 40 + e31] = __float2bfloat16(A2 * B0);
                coefW[7 * 40 + e31] = __float2bfloat16(A2 * B1);
                coefW[8 * 40 + e31] = __float2bfloat16(A2 * B2);
            }

            int rem = dg - g * 32;
#pragma unroll
            for (int t = 0; t < 2; ++t) {             // stage 32 x-rows -> X^T
                int e = 16 * t + (lane >> 2);
                int roe = __shfl(ro, e);
                uint4 v = *(const uint4*)(xbb + roe + (lane & 3) * 16);
                bool vx = e < rem;
                v.x = vx ? v.x : 0u;                  // NaN-safe pad rows
                v.y = vx ? v.y : 0u;
                v.z = vx ? v.z : 0u;
                v.w = vx ? v.w : 0u;
                int c0 = (lane & 3) * 8;
                xtU[(c0 + 0) * 36 + e] = (u16)(v.x);
                xtU[(c0 + 1) * 36 + e] = (u16)(v.x >> 16);
                xtU[(c0 + 2) * 36 + e] = (u16)(v.y);
                xtU[(c0 + 3) * 36 + e] = (u16)(v.y >> 16);
                xtU[(c0 + 4) * 36 + e] = (u16)(v.z);
                xtU[(c0 + 5) * 36 + e] = (u16)(v.z >> 16);
                xtU[(c0 + 6) * 36 + e] = (u16)(v.w);
                xtU[(c0 + 7) * 36 + e] = (u16)(v.w >> 16);
            }

            // A-frag: lane(row=lr plane, k=8*lg+j) -> contiguous 16B
            bf16x8 af = *(const bf16x8*)(coefW + lr * 40 + lg * 8);
            // B-frags: lane(col=ch, k=8*lg+j) from X^T rows ch / ch+16
            const uint2* xlo = (const uint2*)((const char*)xtU + lr * 72 + lg * 16);
            const uint2* xhi = (const uint2*)((const char*)xtU + (lr + 16) * 72 + lg * 16);
            uint2 l0 = xlo[0], l1 = xlo[1];
            uint2 h0 = xhi[0], h1 = xhi[1];
            union UB { unsigned w[4]; bf16x8 v; } bl, bh;
            bl.w[0] = l0.x; bl.w[1] = l0.y; bl.w[2] = l1.x; bl.w[3] = l1.y;
            bh.w[0] = h0.x; bh.w[1] = h0.y; bh.w[2] = h1.x; bh.w[3] = h1.y;
            accL = __builtin_amdgcn_mfma_f32_16x16x32_bf16(af, bl.v, accL, 0, 0, 0);
            accH = __builtin_amdgcn_mfma_f32_16x16x32_bf16(af, bh.v, accH, 0, 0, 0);
        }

        float inv = 1.f / fmaxf((float)dg, 1.f);
#pragma unroll
        for (int r = 0; r < 4; ++r) {                 // C: col=lr, row=lg*4+r
            int p = lg * 4 + r;
            if (p < 9) {
                zlds[rr * RS + p * 32 + lr]      = __float2bfloat16(accL[r] * inv);
                zlds[rr * RS + p * 32 + lr + 16] = __float2bfloat16(accH[r] * inv);
            }
        }
        if (lane < CH) zlds[rr * RS + 288 + lane] = xb[(size_t)n * CH + lane];
    }
    __syncthreads();

    if (wid < 2) {   // wave 0 -> cols 0-15, wave 1 -> cols 16-31
        const bf16* brow = Bg + (size_t)(lr + wid * 16) * RS;
        f32x4 acc = {0.f, 0.f, 0.f, 0.f};
#pragma unroll
        for (int ks = 0; ks < 10; ++ks) {
            int kk = ks * 32 + lg * 8;
            bf16x8 a = *(const bf16x8*)(zlds + lr * RS + kk);
            bf16x8 b = *(const bf16x8*)(brow + kk);        // global, L2-hot
            acc = __builtin_amdgcn_mfma_f32_16x16x32_bf16(a, b, acc, 0, 0, 0);
        }
        float bias = rb[lr + wid * 16];
#pragma unroll
        for (int r = 0; r < 4; ++r) {
            int n = n0 + lg * 4 + r;
            out[(size_t)n * CH + lr + wid * 16] = acc[r] + bias;
        }
    }
}

// ---------------------------------------------------------------------------
extern "C" void kernel_launch(void* const* d_in, const int* in_sizes, int n_in,
                              void* d_out, int out_size, void* d_ws, size_t ws_size,
                              hipStream_t stream) {
    const float* x      = (const float*)d_in[0];
    const float* pseudo = (const float*)d_in[1];
    const float* weight = (const float*)d_in[2];
    const float* root_w = (const float*)d_in[3];
    const float* root_b = (const float*)d_in[4];
    const int*   ei     = (const int*)d_in[5];
    float* out = (float*)d_out;

    int* hist    = (int*)d_ws;                  // 1024 (NBUCK=782 used)
    int* bstart  = hist + 1024;                 // 1024 (NBUCK+1 used)
    int* cursor  = bstart + 1024;               // NBUCK*16 = 12512 (pad 12544)
    int* nstart  = cursor + 12544;              // 100032
    int* ncnt    = nstart + 100032;             // 100032
    char* basep  = (char*)(ncnt + 100032);
    size_t off   = ((size_t)(basep - (char*)d_ws) + 1023) & ~(size_t)1023;
    uint2* edata = (uint2*)((char*)d_ws + off);      // 25.6 MB (+64 record pad)
    bf16* xb     = (bf16*)(edata + N_EDGES + 64);    // 6.4 MB
    bf16* Bg     = xb + (size_t)N_NODES * CH;        // 21 KB

    hipMemsetAsync(hist, 0, NBUCK * sizeof(int), stream);
    prep_kernel<<<(N_NODES * CH / 4 + 255) / 256, 256, 0, stream>>>(x, weight, root_w, xb, Bg);
    bhist_kernel<<<256, 256, 0, stream>>>(ei + N_EDGES, hist);
    bscan_kernel<<<1, 1024, 0, stream>>>(hist, bstart, cursor);
    place_kernel<<<NCHUNK, 1024, 0, stream>>>(pseudo, ei, cursor, edata);
    bsort_kernel<<<NBUCK, 256, 0, stream>>>(bstart, edata, nstart, ncnt);
    gather_mm_kernel<<<N_NODES / 16, 256, 0, stream>>>(xb, Bg, root_b, nstart, ncnt,
                                                       edata, out);
}